// Round 1
// baseline (1013.191 us; speedup 1.0000x reference)
//
#include <hip/hip_runtime.h>
#include <math.h>

#define B_ 4
#define T_ 2048
#define E_ 1024
#define H_ 16
#define D_ 64
#define CHUNK_ 128
#define NC_ 16
#define BH_ (B_ * H_)   // 64
#define M_ (B_ * T_)    // 8192

// ---------------------------------------------------------------------------
// fp32 tiled GEMM core: 128x128 C-tile of A(row-major, K=1024) x B(row-major,
// K=1024)^T. 256 threads, 8x8 micro-tile per thread, BK=16.
// LDS stride 132: 16B-aligned rows, <=2-way bank aliasing (free).
// ---------------------------------------------------------------------------
__device__ __forceinline__ void gemm_core(const float* __restrict__ A,
                                          const float* __restrict__ Bw,
                                          float (*As)[132], float (*Bs)[132],
                                          float acc[8][8]) {
  const int tid = threadIdx.x;
  const int lr = tid >> 2;          // 0..63
  const int lc = (tid & 3) << 2;    // 0,4,8,12
  const int tx = tid & 15, ty = tid >> 4;
  const float* Ap = A + (size_t)lr * 1024 + lc;
  const float* Bp = Bw + (size_t)lr * 1024 + lc;
  for (int kb = 0; kb < 1024; kb += 16) {
    float4 a0 = *(const float4*)(Ap + kb);
    float4 a1 = *(const float4*)(Ap + kb + 64 * 1024);
    float4 b0 = *(const float4*)(Bp + kb);
    float4 b1 = *(const float4*)(Bp + kb + 64 * 1024);
    __syncthreads();  // previous compute done before LDS overwrite
    As[lc + 0][lr] = a0.x; As[lc + 1][lr] = a0.y; As[lc + 2][lr] = a0.z; As[lc + 3][lr] = a0.w;
    As[lc + 0][lr + 64] = a1.x; As[lc + 1][lr + 64] = a1.y; As[lc + 2][lr + 64] = a1.z; As[lc + 3][lr + 64] = a1.w;
    Bs[lc + 0][lr] = b0.x; Bs[lc + 1][lr] = b0.y; Bs[lc + 2][lr] = b0.z; Bs[lc + 3][lr] = b0.w;
    Bs[lc + 0][lr + 64] = b1.x; Bs[lc + 1][lr + 64] = b1.y; Bs[lc + 2][lr + 64] = b1.z; Bs[lc + 3][lr + 64] = b1.w;
    __syncthreads();
#pragma unroll
    for (int k = 0; k < 16; ++k) {
      float a[8], b[8];
      *(float4*)&a[0] = *(const float4*)&As[k][ty * 8];
      *(float4*)&a[4] = *(const float4*)&As[k][ty * 8 + 4];
      *(float4*)&b[0] = *(const float4*)&Bs[k][tx * 8];
      *(float4*)&b[4] = *(const float4*)&Bs[k][tx * 8 + 4];
#pragma unroll
      for (int i = 0; i < 8; ++i)
#pragma unroll
        for (int j = 0; j < 8; ++j)
          acc[i][j] = fmaf(a[i], b[j], acc[i][j]);
    }
  }
}

// ---------------------------------------------------------------------------
// Kernel 1: qkv = x @ w_attn^T, apply phi=elu+1 to q,k, scatter to [B,H,T,D]
// ---------------------------------------------------------------------------
__global__ __launch_bounds__(256) void k_qkv(const float* __restrict__ x,
                                             const float* __restrict__ w,
                                             float* __restrict__ qp,
                                             float* __restrict__ kp,
                                             float* __restrict__ vv) {
  __shared__ float As[16][132], Bs[16][132];
  float acc[8][8] = {};
  const int bm = blockIdx.x, bn = blockIdx.y;
  gemm_core(x + (size_t)bm * 128 * 1024, w + (size_t)bn * 128 * 1024, As, Bs, acc);
  const int tid = threadIdx.x;
  const int tx = tid & 15, ty = tid >> 4;
  const int n0 = bn * 128 + tx * 8;    // 8 consecutive cols, same head/which
  const int which = n0 >> 10;          // 0=q 1=k 2=v
  const int e = n0 & 1023;
  const int h = e >> 6, d0 = e & 63;
  float* dst = (which == 0) ? qp : ((which == 1) ? kp : vv);
#pragma unroll
  for (int i = 0; i < 8; ++i) {
    const int m = bm * 128 + ty * 8 + i;
    const int b = m >> 11, t = m & 2047;
    float* p = dst + (((size_t)(b * H_ + h) * T_ + t) * D_) + d0;
    float o[8];
#pragma unroll
    for (int j = 0; j < 8; ++j) {
      float u = acc[i][j];
      o[j] = (which < 2) ? ((u > 0.f) ? (u + 1.f) : expf(u)) : u;  // elu(u)+1
    }
    *(float4*)&p[0] = *(float4*)&o[0];
    *(float4*)&p[4] = *(float4*)&o[4];
  }
}

// ---------------------------------------------------------------------------
// Kernel 2: per-chunk stats  S_c[d][e] = sum_t k[t][d] v[t][e],  z_c[d]=sum k
// ---------------------------------------------------------------------------
__global__ __launch_bounds__(256) void k_stats(const float* __restrict__ kp,
                                               const float* __restrict__ vv,
                                               float* __restrict__ S,
                                               float* __restrict__ z) {
  __shared__ float ks[128][64], vs[128][64];
  const int blk = blockIdx.x;  // bh*16 + c
  const int bh = blk >> 4, c = blk & 15;
  const int tid = threadIdx.x;
  const float* kc = kp + ((size_t)bh * T_ + c * CHUNK_) * D_;
  const float* vc = vv + ((size_t)bh * T_ + c * CHUNK_) * D_;
#pragma unroll
  for (int s = 0; s < 8; ++s) {
    const int idx = tid + 256 * s;
    ((float4*)ks)[idx] = ((const float4*)kc)[idx];
    ((float4*)vs)[idx] = ((const float4*)vc)[idx];
  }
  __syncthreads();
  const int tx = tid & 15, ty = tid >> 4;
  const int e0 = tx * 4, d0 = ty * 4;
  float acc[4][4] = {};
  float zacc[4] = {0.f, 0.f, 0.f, 0.f};
  for (int t = 0; t < 128; ++t) {
    float4 kd = *(const float4*)&ks[t][d0];
    float4 ve = *(const float4*)&vs[t][e0];
    float kk[4] = {kd.x, kd.y, kd.z, kd.w};
    float vr[4] = {ve.x, ve.y, ve.z, ve.w};
#pragma unroll
    for (int i2 = 0; i2 < 4; ++i2) {
#pragma unroll
      for (int j = 0; j < 4; ++j) acc[i2][j] = fmaf(kk[i2], vr[j], acc[i2][j]);
      zacc[i2] += kk[i2];
    }
  }
  float* Sc = S + (size_t)blk * D_ * D_;
#pragma unroll
  for (int i2 = 0; i2 < 4; ++i2)
    *(float4*)&Sc[(d0 + i2) * 64 + e0] =
        make_float4(acc[i2][0], acc[i2][1], acc[i2][2], acc[i2][3]);
  if (tx == 0) {
    float* zc = z + (size_t)blk * D_;
    *(float4*)&zc[d0] = make_float4(zacc[0], zacc[1], zacc[2], zacc[3]);
  }
}

// ---------------------------------------------------------------------------
// Kernel 3: in-place exclusive prefix over the 16 chunks per (b,h)
// ---------------------------------------------------------------------------
__global__ __launch_bounds__(256) void k_prefix(float* __restrict__ S,
                                                float* __restrict__ z) {
  const int bh = blockIdx.x;
  const int tid = threadIdx.x;
  float4* Sb = (float4*)(S + (size_t)bh * NC_ * 4096);
  float4 acc[4];
#pragma unroll
  for (int j = 0; j < 4; ++j) acc[j] = make_float4(0.f, 0.f, 0.f, 0.f);
  for (int c = 0; c < NC_; ++c) {
#pragma unroll
    for (int j = 0; j < 4; ++j) {
      float4* p = Sb + c * 1024 + tid + 256 * j;
      float4 tv = *p;
      *p = acc[j];
      acc[j].x += tv.x; acc[j].y += tv.y; acc[j].z += tv.z; acc[j].w += tv.w;
    }
  }
  if (tid < 16) {
    float4* zb = (float4*)(z + (size_t)bh * NC_ * 64);
    float4 za = make_float4(0.f, 0.f, 0.f, 0.f);
    for (int c = 0; c < NC_; ++c) {
      float4* q = zb + c * 16 + tid;
      float4 tv = *q;
      *q = za;
      za.x += tv.x; za.y += tv.y; za.z += tv.z; za.w += tv.w;
    }
  }
}

// ---------------------------------------------------------------------------
// Kernel 4: per-chunk output
//   y[i][e] = ( sum_{j<=i} (q_i . k_j) v_j[e]  +  q_i @ S_pre[:,e] )
//             / ( sum_{j<=i} (q_i . k_j) + q_i . z + 1e-6 )
// thread t owns row i = t>>1 and 32 e-cols (e0 = (t&1)*32). q row in regs.
// ---------------------------------------------------------------------------
__global__ __launch_bounds__(256) void k_out(const float* __restrict__ qp,
                                             const float* __restrict__ kp,
                                             const float* __restrict__ vv,
                                             const float* __restrict__ S,
                                             const float* __restrict__ z,
                                             float* __restrict__ y) {
  __shared__ float Ss[64][64];   // 16KB  S_pre
  __shared__ float zs[64];
  __shared__ float kh[64][64];   // 16KB  half of k-chunk
  __shared__ float vh[64][64];   // 16KB  half of v-chunk
  const int blk = blockIdx.x;
  const int bh = blk >> 4, c = blk & 15;
  const int tid = threadIdx.x;
  const int i = tid >> 1;
  const int e0 = (tid & 1) * 32;
  const float* Sc = S + (size_t)blk * 4096;
#pragma unroll
  for (int s = 0; s < 4; ++s)
    ((float4*)Ss)[tid + 256 * s] = ((const float4*)Sc)[tid + 256 * s];
  if (tid < 16) ((float4*)zs)[tid] = ((const float4*)(z + (size_t)blk * 64))[tid];
  const float* qrow = qp + ((size_t)bh * T_ + c * CHUNK_ + i) * D_;
  float qr[64];
#pragma unroll
  for (int s = 0; s < 16; ++s) {
    float4 tv = ((const float4*)qrow)[s];
    qr[4 * s + 0] = tv.x; qr[4 * s + 1] = tv.y;
    qr[4 * s + 2] = tv.z; qr[4 * s + 3] = tv.w;
  }
  __syncthreads();
  float acc[32] = {};
  float den = 0.f;
  // phase 1: q @ S_pre  and  q . z   (all LDS reads wave-uniform broadcasts)
#pragma unroll
  for (int d = 0; d < 64; ++d) {
    const float qd = qr[d];
    den = fmaf(qd, zs[d], den);
#pragma unroll
    for (int jj = 0; jj < 8; ++jj) {
      float4 sv = *(const float4*)&Ss[d][e0 + jj * 4];
      acc[jj * 4 + 0] = fmaf(qd, sv.x, acc[jj * 4 + 0]);
      acc[jj * 4 + 1] = fmaf(qd, sv.y, acc[jj * 4 + 1]);
      acc[jj * 4 + 2] = fmaf(qd, sv.z, acc[jj * 4 + 2]);
      acc[jj * 4 + 3] = fmaf(qd, sv.w, acc[jj * 4 + 3]);
    }
  }
  // phase 2: masked scores + PV, j in two halves of 64
  const float* kcg = kp + ((size_t)bh * T_ + c * CHUNK_) * D_;
  const float* vcg = vv + ((size_t)bh * T_ + c * CHUNK_) * D_;
  for (int jh = 0; jh < 2; ++jh) {
    __syncthreads();
#pragma unroll
    for (int s = 0; s < 4; ++s) {
      const int idx = tid + 256 * s;  // 1024 float4 = 64x64
      ((float4*)kh)[idx] = ((const float4*)(kcg + jh * 64 * 64))[idx];
      ((float4*)vh)[idx] = ((const float4*)(vcg + jh * 64 * 64))[idx];
    }
    __syncthreads();
    if ((i | 31) >= jh * 64) {  // wave-uniform: skip fully-masked halves
      for (int j2 = 0; j2 < 64; ++j2) {
        const int j = jh * 64 + j2;
        float sc = 0.f;
#pragma unroll
        for (int d4 = 0; d4 < 16; ++d4) {
          float4 kk = *(const float4*)&kh[j2][d4 * 4];
          sc = fmaf(qr[d4 * 4 + 0], kk.x, sc);
          sc = fmaf(qr[d4 * 4 + 1], kk.y, sc);
          sc = fmaf(qr[d4 * 4 + 2], kk.z, sc);
          sc = fmaf(qr[d4 * 4 + 3], kk.w, sc);
        }
        sc = (j <= i) ? sc : 0.f;
        den += sc;
#pragma unroll
        for (int jj = 0; jj < 8; ++jj) {
          float4 vr = *(const float4*)&vh[j2][e0 + jj * 4];
          acc[jj * 4 + 0] = fmaf(sc, vr.x, acc[jj * 4 + 0]);
          acc[jj * 4 + 1] = fmaf(sc, vr.y, acc[jj * 4 + 1]);
          acc[jj * 4 + 2] = fmaf(sc, vr.z, acc[jj * 4 + 2]);
          acc[jj * 4 + 3] = fmaf(sc, vr.w, acc[jj * 4 + 3]);
        }
      }
    }
  }
  const float inv = 1.0f / (den + 1e-6f);
  const int b = bh >> 4, h = bh & 15;
  // y layout [B,T,H,D] so the out-proj GEMM reads rows contiguously
  float* yrow = y + (((size_t)(b * T_ + c * CHUNK_ + i) * H_ + h) * D_) + e0;
#pragma unroll
  for (int jj = 0; jj < 8; ++jj) {
    float4 o = make_float4(acc[jj * 4 + 0] * inv, acc[jj * 4 + 1] * inv,
                           acc[jj * 4 + 2] * inv, acc[jj * 4 + 3] * inv);
    *(float4*)&yrow[jj * 4] = o;
  }
}

// ---------------------------------------------------------------------------
// Kernel 5: out = y @ w_proj^T
// ---------------------------------------------------------------------------
__global__ __launch_bounds__(256) void k_proj(const float* __restrict__ y,
                                              const float* __restrict__ w,
                                              float* __restrict__ out) {
  __shared__ float As[16][132], Bs[16][132];
  float acc[8][8] = {};
  const int bm = blockIdx.x, bn = blockIdx.y;
  gemm_core(y + (size_t)bm * 128 * 1024, w + (size_t)bn * 128 * 1024, As, Bs, acc);
  const int tid = threadIdx.x;
  const int tx = tid & 15, ty = tid >> 4;
#pragma unroll
  for (int i = 0; i < 8; ++i) {
    const int m = bm * 128 + ty * 8 + i;
    float* p = out + (size_t)m * 1024 + bn * 128 + tx * 8;
    *(float4*)&p[0] = make_float4(acc[i][0], acc[i][1], acc[i][2], acc[i][3]);
    *(float4*)&p[4] = make_float4(acc[i][4], acc[i][5], acc[i][6], acc[i][7]);
  }
}

// ---------------------------------------------------------------------------
extern "C" void kernel_launch(void* const* d_in, const int* in_sizes, int n_in,
                              void* d_out, int out_size, void* d_ws, size_t ws_size,
                              hipStream_t stream) {
  const float* x = (const float*)d_in[0];
  const float* w_attn = (const float*)d_in[1];
  const float* w_proj = (const float*)d_in[2];
  float* out = (float*)d_out;
  float* ws = (float*)d_ws;

  float* qp = ws;                                  // [B,H,T,D] phi(q)
  float* kp = qp + (size_t)M_ * E_;                // [B,H,T,D] phi(k)
  float* vv = kp + (size_t)M_ * E_;                // [B,H,T,D] v
  float* S = vv + (size_t)M_ * E_;                 // [BH,NC,D,D]
  float* z = S + (size_t)BH_ * NC_ * D_ * D_;      // [BH,NC,D]
  float* y = z + (size_t)BH_ * NC_ * D_;           // [B,T,H,D]

  k_qkv<<<dim3(64, 24), 256, 0, stream>>>(x, w_attn, qp, kp, vv);
  k_stats<<<1024, 256, 0, stream>>>(kp, vv, S, z);
  k_prefix<<<64, 256, 0, stream>>>(S, z);
  k_out<<<1024, 256, 0, stream>>>(qp, kp, vv, S, z, y);
  k_proj<<<dim3(64, 8), 256, 0, stream>>>(y, w_proj, out);
}

// Round 2
// 354.042 us; speedup vs baseline: 2.8618x; 2.8618x over previous
//
#include <hip/hip_runtime.h>
#include <math.h>

#define B_ 4
#define T_ 2048
#define E_ 1024
#define H_ 16
#define D_ 64
#define CHUNK_ 128
#define NC_ 16
#define BH_ (B_ * H_)   // 64
#define M_ (B_ * T_)    // 8192

typedef __attribute__((ext_vector_type(8))) short bf16x8;
typedef __attribute__((ext_vector_type(4))) float f32x4;

__device__ __forceinline__ ushort rnbf(float f) {
  unsigned u = __float_as_uint(f);
  unsigned r = (u + 0x7FFFu + ((u >> 16) & 1u)) >> 16;
  return (ushort)r;
}

__device__ __forceinline__ void gload_lds16(const void* g, void* l) {
  __builtin_amdgcn_global_load_lds(
      (const __attribute__((address_space(1))) unsigned int*)g,
      (__attribute__((address_space(3))) unsigned int*)l, 16, 0, 0);
}

// ---------------------------------------------------------------------------
// fp32 -> bf16 (round-to-nearest) conversion, 4 floats/thread
// ---------------------------------------------------------------------------
__global__ __launch_bounds__(256) void k_cvt(const float* __restrict__ in,
                                             ushort* __restrict__ out, int n4) {
  int i = blockIdx.x * 256 + threadIdx.x;
  if (i < n4) {
    float4 v = ((const float4*)in)[i];
    ushort4 o;
    o.x = rnbf(v.x); o.y = rnbf(v.y); o.z = rnbf(v.z); o.w = rnbf(v.w);
    ((ushort4*)out)[i] = o;
  }
}

// ---------------------------------------------------------------------------
// bf16 MFMA GEMM core (m97 structure): C-tile 128x128 = A[128xK] x B[128xK]^T
// A,B row-major bf16 with K=1024. 256 threads = 4 waves (2x2 of 64x64).
// LDS: linear [128][32] bf16 tiles staged via global_load_lds width=16.
// acc fragment mapping (verified): col = lane&15, row = (lane>>4)*4 + reg.
// ---------------------------------------------------------------------------
__device__ __forceinline__ void mfma_gemm(const ushort* __restrict__ Ag,
                                          const ushort* __restrict__ Bg,
                                          ushort* As, ushort* Bs,
                                          f32x4 acc[4][4]) {
  const int tid = threadIdx.x;
  const int w = tid >> 6, l = tid & 63;
  const int wr = (w >> 1) * 64, wc = (w & 1) * 64;
  const int g8 = (l >> 4) * 8, r16 = l & 15;
  const int srow = l >> 2;          // row within 16-row staging group
  const int scol = (l & 3) * 8;     // k-offset (ushorts) within row
  const int r0 = w * 32;            // this wave's 32-row staging slice

  for (int kb = 0; kb < 1024; kb += 32) {
    gload_lds16(Ag + (size_t)(r0 + srow) * 1024 + kb + scol, &As[r0 * 32]);
    gload_lds16(Ag + (size_t)(r0 + 16 + srow) * 1024 + kb + scol, &As[(r0 + 16) * 32]);
    gload_lds16(Bg + (size_t)(r0 + srow) * 1024 + kb + scol, &Bs[r0 * 32]);
    gload_lds16(Bg + (size_t)(r0 + 16 + srow) * 1024 + kb + scol, &Bs[(r0 + 16) * 32]);
    __syncthreads();  // drains vmcnt -> staged data visible
    bf16x8 af[4], bfr[4];
#pragma unroll
    for (int m = 0; m < 4; ++m)
      af[m] = *(const bf16x8*)&As[(wr + m * 16 + r16) * 32 + g8];
#pragma unroll
    for (int n = 0; n < 4; ++n)
      bfr[n] = *(const bf16x8*)&Bs[(wc + n * 16 + r16) * 32 + g8];
#pragma unroll
    for (int m = 0; m < 4; ++m)
#pragma unroll
      for (int n = 0; n < 4; ++n)
        acc[m][n] = __builtin_amdgcn_mfma_f32_16x16x32_bf16(af[m], bfr[n],
                                                            acc[m][n], 0, 0, 0);
    __syncthreads();  // all reads done before next stage overwrites
  }
}

// ---------------------------------------------------------------------------
// Kernel 1: qkv = x @ w_attn^T (bf16 MFMA), phi on q,k, scatter to [B,H,T,D]
// ---------------------------------------------------------------------------
__global__ __launch_bounds__(256) void k_qkv(const ushort* __restrict__ xb,
                                             const ushort* __restrict__ wab,
                                             float* __restrict__ qp,
                                             float* __restrict__ kp,
                                             float* __restrict__ vv) {
  __shared__ __align__(16) ushort As[4096], Bs[4096];
  f32x4 acc[4][4] = {};
  const int bm = blockIdx.x, bn = blockIdx.y;
  mfma_gemm(xb + (size_t)bm * 128 * 1024, wab + (size_t)bn * 128 * 1024, As, Bs, acc);
  const int tid = threadIdx.x;
  const int w = tid >> 6, l = tid & 63;
  const int wr = (w >> 1) * 64, wc = (w & 1) * 64;
  const int rg4 = (l >> 4) * 4, c16 = l & 15;
#pragma unroll
  for (int n = 0; n < 4; ++n) {
    const int col = bn * 128 + wc + n * 16 + c16;
    const int which = col >> 10;
    const int e = col & 1023;
    const int h = e >> 6, d = e & 63;
    float* dst = (which == 0) ? qp : ((which == 1) ? kp : vv);
#pragma unroll
    for (int m = 0; m < 4; ++m) {
#pragma unroll
      for (int j = 0; j < 4; ++j) {
        const int row = bm * 128 + wr + m * 16 + rg4 + j;
        const int b = row >> 11, t = row & 2047;
        float u = acc[m][n][j];
        float o = (which < 2) ? ((u > 0.f) ? u + 1.f : expf(u)) : u;  // elu+1
        dst[((size_t)(b * H_ + h) * T_ + t) * D_ + d] = o;
      }
    }
  }
}

// ---------------------------------------------------------------------------
// Kernel 2: per-chunk stats  S_c[d][e] = sum_t k[t][d] v[t][e],  z_c[d]=sum k
// ---------------------------------------------------------------------------
__global__ __launch_bounds__(256) void k_stats(const float* __restrict__ kp,
                                               const float* __restrict__ vv,
                                               float* __restrict__ S,
                                               float* __restrict__ z) {
  __shared__ float ks[128][64], vs[128][64];
  const int blk = blockIdx.x;  // bh*16 + c
  const int bh = blk >> 4, c = blk & 15;
  const int tid = threadIdx.x;
  const float* kc = kp + ((size_t)bh * T_ + c * CHUNK_) * D_;
  const float* vc = vv + ((size_t)bh * T_ + c * CHUNK_) * D_;
#pragma unroll
  for (int s = 0; s < 8; ++s) {
    const int idx = tid + 256 * s;
    ((float4*)ks)[idx] = ((const float4*)kc)[idx];
    ((float4*)vs)[idx] = ((const float4*)vc)[idx];
  }
  __syncthreads();
  const int tx = tid & 15, ty = tid >> 4;
  const int e0 = tx * 4, d0 = ty * 4;
  float acc[4][4] = {};
  float zacc[4] = {0.f, 0.f, 0.f, 0.f};
  for (int t = 0; t < 128; ++t) {
    float4 kd = *(const float4*)&ks[t][d0];
    float4 ve = *(const float4*)&vs[t][e0];
    float kk[4] = {kd.x, kd.y, kd.z, kd.w};
    float vr[4] = {ve.x, ve.y, ve.z, ve.w};
#pragma unroll
    for (int i2 = 0; i2 < 4; ++i2) {
#pragma unroll
      for (int j = 0; j < 4; ++j) acc[i2][j] = fmaf(kk[i2], vr[j], acc[i2][j]);
      zacc[i2] += kk[i2];
    }
  }
  float* Sc = S + (size_t)blk * D_ * D_;
#pragma unroll
  for (int i2 = 0; i2 < 4; ++i2)
    *(float4*)&Sc[(d0 + i2) * 64 + e0] =
        make_float4(acc[i2][0], acc[i2][1], acc[i2][2], acc[i2][3]);
  if (tx == 0) {
    float* zc = z + (size_t)blk * D_;
    *(float4*)&zc[d0] = make_float4(zacc[0], zacc[1], zacc[2], zacc[3]);
  }
}

// ---------------------------------------------------------------------------
// Kernel 3: in-place exclusive prefix over the 16 chunks per (b,h)
// ---------------------------------------------------------------------------
__global__ __launch_bounds__(256) void k_prefix(float* __restrict__ S,
                                                float* __restrict__ z) {
  const int bh = blockIdx.x;
  const int tid = threadIdx.x;
  float4* Sb = (float4*)(S + (size_t)bh * NC_ * 4096);
  float4 acc[4];
#pragma unroll
  for (int j = 0; j < 4; ++j) acc[j] = make_float4(0.f, 0.f, 0.f, 0.f);
  for (int c = 0; c < NC_; ++c) {
#pragma unroll
    for (int j = 0; j < 4; ++j) {
      float4* p = Sb + c * 1024 + tid + 256 * j;
      float4 tv = *p;
      *p = acc[j];
      acc[j].x += tv.x; acc[j].y += tv.y; acc[j].z += tv.z; acc[j].w += tv.w;
    }
  }
  if (tid < 16) {
    float4* zb = (float4*)(z + (size_t)bh * NC_ * 64);
    float4 za = make_float4(0.f, 0.f, 0.f, 0.f);
    for (int c = 0; c < NC_; ++c) {
      float4* q = zb + c * 16 + tid;
      float4 tv = *q;
      *q = za;
      za.x += tv.x; za.y += tv.y; za.z += tv.z; za.w += tv.w;
    }
  }
}

// ---------------------------------------------------------------------------
// Kernel 4: per-chunk output (fp32), writes y as bf16 [B,T,H,D]
// ---------------------------------------------------------------------------
__global__ __launch_bounds__(256) void k_out(const float* __restrict__ qp,
                                             const float* __restrict__ kp,
                                             const float* __restrict__ vv,
                                             const float* __restrict__ S,
                                             const float* __restrict__ z,
                                             ushort* __restrict__ yb) {
  __shared__ float Ss[64][64];
  __shared__ float zs[64];
  __shared__ float kh[64][64];
  __shared__ float vh[64][64];
  const int blk = blockIdx.x;
  const int bh = blk >> 4, c = blk & 15;
  const int tid = threadIdx.x;
  const int i = tid >> 1;
  const int e0 = (tid & 1) * 32;
  const float* Sc = S + (size_t)blk * 4096;
#pragma unroll
  for (int s = 0; s < 4; ++s)
    ((float4*)Ss)[tid + 256 * s] = ((const float4*)Sc)[tid + 256 * s];
  if (tid < 16) ((float4*)zs)[tid] = ((const float4*)(z + (size_t)blk * 64))[tid];
  const float* qrow = qp + ((size_t)bh * T_ + c * CHUNK_ + i) * D_;
  float qr[64];
#pragma unroll
  for (int s = 0; s < 16; ++s) {
    float4 tv = ((const float4*)qrow)[s];
    qr[4 * s + 0] = tv.x; qr[4 * s + 1] = tv.y;
    qr[4 * s + 2] = tv.z; qr[4 * s + 3] = tv.w;
  }
  __syncthreads();
  float acc[32] = {};
  float den = 0.f;
#pragma unroll
  for (int d = 0; d < 64; ++d) {
    const float qd = qr[d];
    den = fmaf(qd, zs[d], den);
#pragma unroll
    for (int jj = 0; jj < 8; ++jj) {
      float4 sv = *(const float4*)&Ss[d][e0 + jj * 4];
      acc[jj * 4 + 0] = fmaf(qd, sv.x, acc[jj * 4 + 0]);
      acc[jj * 4 + 1] = fmaf(qd, sv.y, acc[jj * 4 + 1]);
      acc[jj * 4 + 2] = fmaf(qd, sv.z, acc[jj * 4 + 2]);
      acc[jj * 4 + 3] = fmaf(qd, sv.w, acc[jj * 4 + 3]);
    }
  }
  const float* kcg = kp + ((size_t)bh * T_ + c * CHUNK_) * D_;
  const float* vcg = vv + ((size_t)bh * T_ + c * CHUNK_) * D_;
  for (int jh = 0; jh < 2; ++jh) {
    __syncthreads();
#pragma unroll
    for (int s = 0; s < 4; ++s) {
      const int idx = tid + 256 * s;
      ((float4*)kh)[idx] = ((const float4*)(kcg + jh * 64 * 64))[idx];
      ((float4*)vh)[idx] = ((const float4*)(vcg + jh * 64 * 64))[idx];
    }
    __syncthreads();
    if ((i | 31) >= jh * 64) {
      for (int j2 = 0; j2 < 64; ++j2) {
        const int j = jh * 64 + j2;
        float sc = 0.f;
#pragma unroll
        for (int d4 = 0; d4 < 16; ++d4) {
          float4 kk = *(const float4*)&kh[j2][d4 * 4];
          sc = fmaf(qr[d4 * 4 + 0], kk.x, sc);
          sc = fmaf(qr[d4 * 4 + 1], kk.y, sc);
          sc = fmaf(qr[d4 * 4 + 2], kk.z, sc);
          sc = fmaf(qr[d4 * 4 + 3], kk.w, sc);
        }
        sc = (j <= i) ? sc : 0.f;
        den += sc;
#pragma unroll
        for (int jj = 0; jj < 8; ++jj) {
          float4 vr = *(const float4*)&vh[j2][e0 + jj * 4];
          acc[jj * 4 + 0] = fmaf(sc, vr.x, acc[jj * 4 + 0]);
          acc[jj * 4 + 1] = fmaf(sc, vr.y, acc[jj * 4 + 1]);
          acc[jj * 4 + 2] = fmaf(sc, vr.z, acc[jj * 4 + 2]);
          acc[jj * 4 + 3] = fmaf(sc, vr.w, acc[jj * 4 + 3]);
        }
      }
    }
  }
  const float inv = 1.0f / (den + 1e-6f);
  const int b = bh >> 4, h = bh & 15;
  ushort* yrow = yb + (((size_t)(b * T_ + c * CHUNK_ + i) * H_ + h) * D_) + e0;
  __align__(16) ushort ob[32];
#pragma unroll
  for (int jj = 0; jj < 32; ++jj) ob[jj] = rnbf(acc[jj] * inv);
#pragma unroll
  for (int s = 0; s < 4; ++s) ((uint4*)yrow)[s] = ((const uint4*)ob)[s];
}

// ---------------------------------------------------------------------------
// Kernel 5: out = y @ w_proj^T (bf16 MFMA), fp32 output
// ---------------------------------------------------------------------------
__global__ __launch_bounds__(256) void k_proj(const ushort* __restrict__ yb,
                                              const ushort* __restrict__ wpb,
                                              float* __restrict__ out) {
  __shared__ __align__(16) ushort As[4096], Bs[4096];
  f32x4 acc[4][4] = {};
  const int bm = blockIdx.x, bn = blockIdx.y;
  mfma_gemm(yb + (size_t)bm * 128 * 1024, wpb + (size_t)bn * 128 * 1024, As, Bs, acc);
  const int tid = threadIdx.x;
  const int w = tid >> 6, l = tid & 63;
  const int wr = (w >> 1) * 64, wc = (w & 1) * 64;
  const int rg4 = (l >> 4) * 4, c16 = l & 15;
#pragma unroll
  for (int m = 0; m < 4; ++m)
#pragma unroll
    for (int n = 0; n < 4; ++n)
#pragma unroll
      for (int j = 0; j < 4; ++j) {
        const int row = bm * 128 + wr + m * 16 + rg4 + j;
        const int col = bn * 128 + wc + n * 16 + c16;
        out[(size_t)row * 1024 + col] = acc[m][n][j];
      }
}

// ---------------------------------------------------------------------------
extern "C" void kernel_launch(void* const* d_in, const int* in_sizes, int n_in,
                              void* d_out, int out_size, void* d_ws, size_t ws_size,
                              hipStream_t stream) {
  const float* x = (const float*)d_in[0];
  const float* w_attn = (const float*)d_in[1];
  const float* w_proj = (const float*)d_in[2];
  float* out = (float*)d_out;

  // workspace layout (region A is reused: bf16 inputs first, then S/z)
  ushort* xb = (ushort*)d_ws;                       // 16.78 MB  [8192,1024] bf16
  ushort* wab = xb + (size_t)M_ * E_;               //  6.29 MB  [3072,1024] bf16
  float* S = (float*)d_ws;                          // 16.78 MB  overlays xb
  float* z = S + (size_t)BH_ * NC_ * D_ * D_;       //  0.26 MB  overlays wab head
  float* qp = (float*)(wab + (size_t)3 * E_ * E_);  // 33.55 MB
  float* kp = qp + (size_t)M_ * E_;                 // 33.55 MB
  float* vv = kp + (size_t)M_ * E_;                 // 33.55 MB
  ushort* yb = (ushort*)(vv + (size_t)M_ * E_);     // 16.78 MB  [B,T,H,D] bf16
  ushort* wpb = yb + (size_t)M_ * E_;               //  2.10 MB

  k_cvt<<<8192, 256, 0, stream>>>(x, xb, (M_ * E_) / 4);
  k_cvt<<<3072, 256, 0, stream>>>(w_attn, wab, (3 * E_ * E_) / 4);
  k_cvt<<<1024, 256, 0, stream>>>(w_proj, wpb, (E_ * E_) / 4);
  k_qkv<<<dim3(64, 24), 256, 0, stream>>>(xb, wab, qp, kp, vv);
  k_stats<<<1024, 256, 0, stream>>>(kp, vv, S, z);
  k_prefix<<<64, 256, 0, stream>>>(S, z);
  k_out<<<1024, 256, 0, stream>>>(qp, kp, vv, S, z, yb);
  k_proj<<<dim3(64, 8), 256, 0, stream>>>(yb, wpb, out);
}

// Round 3
// 173.602 us; speedup vs baseline: 5.8363x; 2.0394x over previous
//
#include <hip/hip_runtime.h>
#include <math.h>

#define B_ 4
#define T_ 2048
#define E_ 1024
#define H_ 16
#define D_ 64
#define CHUNK_ 128
#define NC_ 16
#define BH_ (B_ * H_)   // 64
#define M_ (B_ * T_)    // 8192

typedef __attribute__((ext_vector_type(8))) short bf16x8;
typedef __attribute__((ext_vector_type(4))) float f32x4;

__device__ __forceinline__ ushort rnbf(float f) {
  unsigned u = __float_as_uint(f);
  unsigned r = (u + 0x7FFFu + ((u >> 16) & 1u)) >> 16;
  return (ushort)r;
}

__device__ __forceinline__ float bf2f(short s) {
  return __uint_as_float(((unsigned)(ushort)s) << 16);
}

__device__ __forceinline__ void gload_lds16(const void* g, void* l) {
  __builtin_amdgcn_global_load_lds(
      (const __attribute__((address_space(1))) unsigned int*)g,
      (__attribute__((address_space(3))) unsigned int*)l, 16, 0, 0);
}

// ---------------------------------------------------------------------------
// fp32 -> bf16 conversion
// ---------------------------------------------------------------------------
__global__ __launch_bounds__(256) void k_cvt(const float* __restrict__ in,
                                             ushort* __restrict__ out, int n4) {
  int i = blockIdx.x * 256 + threadIdx.x;
  if (i < n4) {
    float4 v = ((const float4*)in)[i];
    ushort4 o;
    o.x = rnbf(v.x); o.y = rnbf(v.y); o.z = rnbf(v.z); o.w = rnbf(v.w);
    ((ushort4*)out)[i] = o;
  }
}

// ---------------------------------------------------------------------------
// bf16 MFMA GEMM core, 128x128 tile, (row&3) LDS block swizzle (4-way max)
// ---------------------------------------------------------------------------
__device__ __forceinline__ void mfma_gemm(const ushort* __restrict__ Ag,
                                          const ushort* __restrict__ Bg,
                                          ushort* As, ushort* Bs,
                                          f32x4 acc[4][4]) {
  const int tid = threadIdx.x;
  const int w = tid >> 6, l = tid & 63;
  const int wr = (w >> 1) * 64, wc = (w & 1) * 64;
  const int g8 = (l >> 4) * 8, r16 = l & 15;
  const int srow = l >> 2;
  const int scol = (((l & 3) ^ (srow & 3)) * 8);  // pre-swizzled source block
  const int r0 = w * 32;
  const int xo = g8 ^ ((r16 & 3) << 3);           // swizzled read offset

  for (int kb = 0; kb < 1024; kb += 32) {
    gload_lds16(Ag + (size_t)(r0 + srow) * 1024 + kb + scol, &As[r0 * 32]);
    gload_lds16(Ag + (size_t)(r0 + 16 + srow) * 1024 + kb + scol, &As[(r0 + 16) * 32]);
    gload_lds16(Bg + (size_t)(r0 + srow) * 1024 + kb + scol, &Bs[r0 * 32]);
    gload_lds16(Bg + (size_t)(r0 + 16 + srow) * 1024 + kb + scol, &Bs[(r0 + 16) * 32]);
    __syncthreads();
    bf16x8 af[4], bfr[4];
#pragma unroll
    for (int m = 0; m < 4; ++m)
      af[m] = *(const bf16x8*)&As[(wr + m * 16 + r16) * 32 + xo];
#pragma unroll
    for (int n = 0; n < 4; ++n)
      bfr[n] = *(const bf16x8*)&Bs[(wc + n * 16 + r16) * 32 + xo];
#pragma unroll
    for (int m = 0; m < 4; ++m)
#pragma unroll
      for (int n = 0; n < 4; ++n)
        acc[m][n] = __builtin_amdgcn_mfma_f32_16x16x32_bf16(af[m], bfr[n],
                                                            acc[m][n], 0, 0, 0);
    __syncthreads();
  }
}

// ---------------------------------------------------------------------------
// Kernel 1: qkv GEMM + phi; emits qb,kb [bh][t][d] and kT,vT [bh][d][t] bf16
// ---------------------------------------------------------------------------
__global__ __launch_bounds__(256) void k_qkv(const ushort* __restrict__ xb,
                                             const ushort* __restrict__ wab,
                                             ushort* __restrict__ qg,
                                             ushort* __restrict__ kg,
                                             ushort* __restrict__ ktg,
                                             ushort* __restrict__ vtg) {
  __shared__ __align__(16) ushort As[4096], Bs[4096];
  f32x4 acc[4][4] = {};
  const int bm = blockIdx.x, bn = blockIdx.y;
  mfma_gemm(xb + (size_t)bm * 128 * 1024, wab + (size_t)bn * 128 * 1024, As, Bs, acc);
  const int tid = threadIdx.x;
  const int w = tid >> 6, l = tid & 63;
  const int wr = (w >> 1) * 64, wc = (w & 1) * 64;
  const int rg4 = (l >> 4) * 4, c16 = l & 15;
#pragma unroll
  for (int n = 0; n < 4; ++n) {
    const int col = bn * 128 + wc + n * 16 + c16;
    const int which = col >> 10;
    const int e = col & 1023;
    const int h = e >> 6, d = e & 63;
#pragma unroll
    for (int m = 0; m < 4; ++m) {
      const int row0 = bm * 128 + wr + m * 16 + rg4;
      const int b = row0 >> 11, t0 = row0 & 2047;
      const size_t bh = (size_t)(b * H_ + h);
      ushort u[4];
#pragma unroll
      for (int j = 0; j < 4; ++j) {
        float v = acc[m][n][j];
        if (which < 2) v = (v > 0.f) ? v + 1.f : expf(v);  // elu+1
        u[j] = rnbf(v);
      }
      if (which == 0) {
#pragma unroll
        for (int j = 0; j < 4; ++j) qg[(bh * T_ + t0 + j) * D_ + d] = u[j];
      } else if (which == 1) {
#pragma unroll
        for (int j = 0; j < 4; ++j) kg[(bh * T_ + t0 + j) * D_ + d] = u[j];
        ushort4 uv; uv.x = u[0]; uv.y = u[1]; uv.z = u[2]; uv.w = u[3];
        *(ushort4*)&ktg[(bh * D_ + d) * T_ + t0] = uv;
      } else {
        ushort4 uv; uv.x = u[0]; uv.y = u[1]; uv.z = u[2]; uv.w = u[3];
        *(ushort4*)&vtg[(bh * D_ + d) * T_ + t0] = uv;
      }
    }
  }
}

// ---------------------------------------------------------------------------
// Kernel 2 (MFMA): per-chunk  ST[e][d] = sum_t v[t][e] k[t][d]  (fp32 out)
//                  z[d] = sum_t k[t][d]
// ---------------------------------------------------------------------------
__global__ __launch_bounds__(256) void k_stats(const ushort* __restrict__ ktg,
                                               const ushort* __restrict__ vtg,
                                               const ushort* __restrict__ kg,
                                               float* __restrict__ Sc,
                                               float* __restrict__ zg) {
  __shared__ __align__(16) ushort kT_s[64 * 128], vT_s[64 * 128];
  __shared__ float zred[4][64];
  const int blk = blockIdx.x;
  const int bh = blk >> 4, c = blk & 15;
  const int tid = threadIdx.x;
  const int w = tid >> 6, l = tid & 63;
  const ushort* ktb = ktg + (size_t)bh * D_ * T_ + c * CHUNK_;
  const ushort* vtb = vtg + (size_t)bh * D_ * T_ + c * CHUNK_;
#pragma unroll
  for (int s2 = 0; s2 < 4; ++s2) {
    const int seg = w * 4 + s2;
    const int row = seg * 4 + (l >> 4);
    const int sb = ((l & 15) ^ (row & 7)) * 8;
    gload_lds16(ktb + (size_t)row * T_ + sb, &kT_s[seg * 512]);
    gload_lds16(vtb + (size_t)row * T_ + sb, &vT_s[seg * 512]);
  }
  // z partials from kb (coalesced) while staging is in flight
  {
    const int d = tid & 63, part = tid >> 6;
    float zp = 0.f;
    const ushort* kpart = kg + ((size_t)bh * T_ + c * CHUNK_ + part * 32) * D_ + d;
#pragma unroll
    for (int r = 0; r < 32; ++r) zp += bf2f((short)kpart[r * 64]);
    zred[part][d] = zp;
  }
  __syncthreads();
  if (tid < 64)
    zg[((size_t)bh * NC_ + c) * 64 + tid] =
        zred[0][tid] + zred[1][tid] + zred[2][tid] + zred[3][tid];
  const int wr = w >> 1, wc = w & 1;
  f32x4 acc[2][2] = {};
#pragma unroll
  for (int kt = 0; kt < 4; ++kt) {
    const int g = kt * 32 + (l >> 4) * 8;
    bf16x8 av[2], bk[2];
#pragma unroll
    for (int rt = 0; rt < 2; ++rt) {
      const int e = wr * 32 + rt * 16 + (l & 15);
      av[rt] = *(const bf16x8*)&vT_s[e * 128 + (g ^ ((e & 7) << 3))];
    }
#pragma unroll
    for (int ct = 0; ct < 2; ++ct) {
      const int d = wc * 32 + ct * 16 + (l & 15);
      bk[ct] = *(const bf16x8*)&kT_s[d * 128 + (g ^ ((d & 7) << 3))];
    }
#pragma unroll
    for (int rt = 0; rt < 2; ++rt)
#pragma unroll
      for (int ct = 0; ct < 2; ++ct)
        acc[rt][ct] = __builtin_amdgcn_mfma_f32_16x16x32_bf16(av[rt], bk[ct],
                                                              acc[rt][ct], 0, 0, 0);
  }
  float* So = Sc + (size_t)blk * 4096;
#pragma unroll
  for (int rt = 0; rt < 2; ++rt)
#pragma unroll
    for (int ct = 0; ct < 2; ++ct)
#pragma unroll
      for (int jj = 0; jj < 4; ++jj)
        So[(wr * 32 + rt * 16 + (l >> 4) * 4 + jj) * 64 + wc * 32 + ct * 16 + (l & 15)] =
            acc[rt][ct][jj];
}

// ---------------------------------------------------------------------------
// Kernel 3: exclusive prefix over 16 chunks; fp32 in, bf16 ST out, fp32 z out
// ---------------------------------------------------------------------------
__global__ __launch_bounds__(256) void k_prefix(const float* __restrict__ Sc,
                                                ushort* __restrict__ STb,
                                                float* __restrict__ z) {
  const int bh = blockIdx.x;
  const int tid = threadIdx.x;
  const float4* Sb = (const float4*)(Sc + (size_t)bh * NC_ * 4096);
  ushort4* Ob = (ushort4*)(STb + (size_t)bh * NC_ * 4096);
  float4 acc[4];
#pragma unroll
  for (int j = 0; j < 4; ++j) acc[j] = make_float4(0.f, 0.f, 0.f, 0.f);
  for (int c = 0; c < NC_; ++c) {
#pragma unroll
    for (int j = 0; j < 4; ++j) {
      const int idx = c * 1024 + tid + 256 * j;
      float4 tv = Sb[idx];
      ushort4 o;
      o.x = rnbf(acc[j].x); o.y = rnbf(acc[j].y);
      o.z = rnbf(acc[j].z); o.w = rnbf(acc[j].w);
      Ob[idx] = o;
      acc[j].x += tv.x; acc[j].y += tv.y; acc[j].z += tv.z; acc[j].w += tv.w;
    }
  }
  if (tid < 16) {
    float4* zb = (float4*)(z + (size_t)bh * NC_ * 64);
    float4 za = make_float4(0.f, 0.f, 0.f, 0.f);
    for (int c = 0; c < NC_; ++c) {
      float4* q = zb + c * 16 + tid;
      float4 tv = *q;
      *q = za;
      za.x += tv.x; za.y += tv.y; za.z += tv.z; za.w += tv.w;
    }
  }
}

// ---------------------------------------------------------------------------
// Kernel 4 (MFMA): per-chunk output. 512 thr = 8 waves, 16 q-rows each.
//   scores = q k^T (masked, fp32 rowsum for den) -> P bf16 in LDS
//   y = (P v + q ST^T) / (rowsum + q.z + 1e-6)  -> bf16 [B,T,H,D]
// ---------------------------------------------------------------------------
__global__ __launch_bounds__(512, 4) void k_out(
    const ushort* __restrict__ qg, const ushort* __restrict__ kg,
    const ushort* __restrict__ vtg, const ushort* __restrict__ STb,
    const float* __restrict__ zg, ushort* __restrict__ yb) {
  __shared__ __align__(16) ushort k_s[128 * 64];    // 16K, 8 blk/row, ^(row&7)
  __shared__ __align__(16) ushort vT_s[64 * 128];   // 16K, 16 blk/row
  __shared__ __align__(16) ushort ST_s[64 * 64];    // 8K
  __shared__ __align__(16) ushort P_s[128 * 128];   // 32K
  __shared__ float z_s[64];
  __shared__ float dinter_s[128];
  const int blk = blockIdx.x;
  const int bh = blk >> 4, c = blk & 15;
  const int tid = threadIdx.x;
  const int w = tid >> 6, l = tid & 63;

  const ushort* kbase = kg + ((size_t)bh * T_ + c * CHUNK_) * D_;
  const ushort* vbase = vtg + (size_t)bh * D_ * T_ + c * CHUNK_;
  const ushort* sbase = STb + ((size_t)bh * NC_ + c) * 4096;
  {  // k: 16 segs x 8 rows
    int seg = w, row = seg * 8 + (l >> 3);
    gload_lds16(kbase + (size_t)row * 64 + ((l & 7) ^ (row & 7)) * 8, &k_s[seg * 512]);
    seg = w + 8; row = seg * 8 + (l >> 3);
    gload_lds16(kbase + (size_t)row * 64 + ((l & 7) ^ (row & 7)) * 8, &k_s[seg * 512]);
  }
  {  // vT: 16 segs x 4 rows (global row stride T_)
    int seg = w, row = seg * 4 + (l >> 4);
    gload_lds16(vbase + (size_t)row * T_ + ((l & 15) ^ (row & 7)) * 8, &vT_s[seg * 512]);
    seg = w + 8; row = seg * 4 + (l >> 4);
    gload_lds16(vbase + (size_t)row * T_ + ((l & 15) ^ (row & 7)) * 8, &vT_s[seg * 512]);
  }
  {  // ST: 8 segs x 8 rows
    const int seg = w, row = seg * 8 + (l >> 3);
    gload_lds16(sbase + (size_t)row * 64 + ((l & 7) ^ (row & 7)) * 8, &ST_s[seg * 512]);
  }
  if (tid < 64) z_s[tid] = zg[((size_t)bh * NC_ + c) * 64 + tid];
  // q A-fragments (row = w*16 + (l&15))
  const int arow = w * 16 + (l & 15);
  const ushort* qrow = qg + ((size_t)bh * T_ + c * CHUNK_ + arow) * D_ + (l >> 4) * 8;
  bf16x8 qf0 = *(const bf16x8*)(qrow);
  bf16x8 qf1 = *(const bf16x8*)(qrow + 32);
  __syncthreads();

  // ---- QK^T (K = d = 64)
  f32x4 sc[8] = {};
#pragma unroll
  for (int jt = 0; jt < 8; ++jt) {
    const int j = jt * 16 + (l & 15);
    const int sw = (j & 7) << 3, g = (l >> 4) * 8;
    bf16x8 b0 = *(const bf16x8*)&k_s[j * 64 + (g ^ sw)];
    bf16x8 b1 = *(const bf16x8*)&k_s[j * 64 + ((g + 32) ^ sw)];
    sc[jt] = __builtin_amdgcn_mfma_f32_16x16x32_bf16(qf0, b0, sc[jt], 0, 0, 0);
    sc[jt] = __builtin_amdgcn_mfma_f32_16x16x32_bf16(qf1, b1, sc[jt], 0, 0, 0);
  }
  // ---- mask, rowsum, P -> LDS (bf16, swizzled)
  const int crow0 = w * 16 + (l >> 4) * 4;
  float rsum[4] = {0.f, 0.f, 0.f, 0.f};
#pragma unroll
  for (int jt = 0; jt < 8; ++jt) {
    const int j = jt * 16 + (l & 15);
#pragma unroll
    for (int jj = 0; jj < 4; ++jj) {
      const int i = crow0 + jj;
      float s = (j <= i) ? sc[jt][jj] : 0.f;
      rsum[jj] += s;
      P_s[i * 128 + (j ^ ((i & 7) << 3))] = rnbf(s);
    }
  }
  // den_inter = q . z (A-layout row = l&15), reduce over k-groups
  float di = 0.f;
#pragma unroll
  for (int jj = 0; jj < 8; ++jj) {
    di = fmaf(bf2f(qf0[jj]), z_s[(l >> 4) * 8 + jj], di);
    di = fmaf(bf2f(qf1[jj]), z_s[32 + (l >> 4) * 8 + jj], di);
  }
  di += __shfl_xor(di, 16);
  di += __shfl_xor(di, 32);
  if (l < 16) dinter_s[w * 16 + l] = di;
  // rowsum reduce across the 16 cols held per lane group
#pragma unroll
  for (int jj = 0; jj < 4; ++jj) {
    float r = rsum[jj];
    r += __shfl_xor(r, 1); r += __shfl_xor(r, 2);
    r += __shfl_xor(r, 4); r += __shfl_xor(r, 8);
    rsum[jj] = r;
  }
  __syncthreads();

  // ---- acc2 = q @ ST^T + P @ v
  f32x4 acc2[4] = {};
#pragma unroll
  for (int et = 0; et < 4; ++et) {
    const int e = et * 16 + (l & 15);
    const int sw = (e & 7) << 3, g = (l >> 4) * 8;
    bf16x8 s0 = *(const bf16x8*)&ST_s[e * 64 + (g ^ sw)];
    bf16x8 s1 = *(const bf16x8*)&ST_s[e * 64 + ((g + 32) ^ sw)];
    acc2[et] = __builtin_amdgcn_mfma_f32_16x16x32_bf16(qf0, s0, acc2[et], 0, 0, 0);
    acc2[et] = __builtin_amdgcn_mfma_f32_16x16x32_bf16(qf1, s1, acc2[et], 0, 0, 0);
  }
  const int prow = w * 16 + (l & 15);
  const int psw = (prow & 7) << 3;
#pragma unroll
  for (int jkt = 0; jkt < 4; ++jkt) {
    bf16x8 pa = *(const bf16x8*)&P_s[prow * 128 + ((jkt * 32 + (l >> 4) * 8) ^ psw)];
#pragma unroll
    for (int et = 0; et < 4; ++et) {
      const int e = et * 16 + (l & 15);
      bf16x8 bv = *(const bf16x8*)&vT_s[e * 128 +
                                        ((jkt * 32 + (l >> 4) * 8) ^ ((e & 7) << 3))];
      acc2[et] = __builtin_amdgcn_mfma_f32_16x16x32_bf16(pa, bv, acc2[et], 0, 0, 0);
    }
  }
  // ---- divide + store y bf16 [B,T,H,D]
  float inv[4];
#pragma unroll
  for (int jj = 0; jj < 4; ++jj)
    inv[jj] = 1.0f / (rsum[jj] + dinter_s[crow0 + jj] + 1e-6f);
  const int b = bh >> 4, h = bh & 15;
#pragma unroll
  for (int et = 0; et < 4; ++et) {
    const int d = et * 16 + (l & 15);
#pragma unroll
    for (int jj = 0; jj < 4; ++jj) {
      const int t = c * CHUNK_ + crow0 + jj;
      yb[((size_t)(b * T_ + t) * H_ + h) * D_ + d] = rnbf(acc2[et][jj] * inv[jj]);
    }
  }
}

// ---------------------------------------------------------------------------
// Kernel 5: out = y @ w_proj^T (bf16 MFMA), fp32 out
// ---------------------------------------------------------------------------
__global__ __launch_bounds__(256) void k_proj(const ushort* __restrict__ yb,
                                              const ushort* __restrict__ wpb,
                                              float* __restrict__ out) {
  __shared__ __align__(16) ushort As[4096], Bs[4096];
  f32x4 acc[4][4] = {};
  const int bm = blockIdx.x, bn = blockIdx.y;
  mfma_gemm(yb + (size_t)bm * 128 * 1024, wpb + (size_t)bn * 128 * 1024, As, Bs, acc);
  const int tid = threadIdx.x;
  const int w = tid >> 6, l = tid & 63;
  const int wr = (w >> 1) * 64, wc = (w & 1) * 64;
  const int rg4 = (l >> 4) * 4, c16 = l & 15;
#pragma unroll
  for (int m = 0; m < 4; ++m)
#pragma unroll
    for (int n = 0; n < 4; ++n)
#pragma unroll
      for (int j = 0; j < 4; ++j) {
        const int row = bm * 128 + wr + m * 16 + rg4 + j;
        const int col = bn * 128 + wc + n * 16 + c16;
        out[(size_t)row * 1024 + col] = acc[m][n][j];
      }
}

// ---------------------------------------------------------------------------
extern "C" void kernel_launch(void* const* d_in, const int* in_sizes, int n_in,
                              void* d_out, int out_size, void* d_ws, size_t ws_size,
                              hipStream_t stream) {
  const float* x = (const float*)d_in[0];
  const float* w_attn = (const float*)d_in[1];
  const float* w_proj = (const float*)d_in[2];
  float* out = (float*)d_out;

  ushort* xb = (ushort*)d_ws;                        // [8192,1024]
  ushort* wab = xb + (size_t)M_ * E_;                // [3072,1024]
  ushort* wpb = wab + (size_t)3 * E_ * E_;           // [1024,1024]
  ushort* qb = wpb + (size_t)E_ * E_;                // [bh][t][d]
  ushort* kbm = qb + (size_t)M_ * E_;                // [bh][t][d]
  ushort* kT = kbm + (size_t)M_ * E_;                // [bh][d][t]
  ushort* vT = kT + (size_t)M_ * E_;                 // [bh][d][t]
  ushort* yb = vT + (size_t)M_ * E_;                 // [B,T,H,D]
  ushort* STb = yb + (size_t)M_ * E_;                // [bh][c][e][d] bf16
  float* Schunk = (float*)(STb + (size_t)BH_ * NC_ * 4096);  // [bh][c][e][d] f32
  float* zbuf = Schunk + (size_t)BH_ * NC_ * 4096;   // [bh][c][d] f32

  k_cvt<<<8192, 256, 0, stream>>>(x, xb, (M_ * E_) / 4);
  k_cvt<<<3072, 256, 0, stream>>>(w_attn, wab, (3 * E_ * E_) / 4);
  k_cvt<<<1024, 256, 0, stream>>>(w_proj, wpb, (E_ * E_) / 4);
  k_qkv<<<dim3(64, 24), 256, 0, stream>>>(xb, wab, qb, kbm, kT, vT);
  k_stats<<<1024, 256, 0, stream>>>(kT, vT, kbm, Schunk, zbuf);
  k_prefix<<<64, 256, 0, stream>>>(Schunk, STb, zbuf);
  k_out<<<1024, 512, 0, stream>>>(qb, kbm, vT, STb, zbuf, yb);
  k_proj<<<dim3(64, 8), 256, 0, stream>>>(yb, wpb, out);
}

// Round 4
// 168.030 us; speedup vs baseline: 6.0298x; 1.0332x over previous
//
#include <hip/hip_runtime.h>
#include <math.h>

#define B_ 4
#define T_ 2048
#define E_ 1024
#define H_ 16
#define D_ 64
#define CHUNK_ 128
#define NC_ 16
#define BH_ (B_ * H_)   // 64
#define M_ (B_ * T_)    // 8192
#define NKT_ 16         // K tiles of 64 in qkv GEMM

typedef __attribute__((ext_vector_type(8))) short bf16x8;
typedef __attribute__((ext_vector_type(4))) float f32x4;

__device__ __forceinline__ ushort rnbf(float f) {
  unsigned u = __float_as_uint(f);
  unsigned r = (u + 0x7FFFu + ((u >> 16) & 1u)) >> 16;
  return (ushort)r;
}

__device__ __forceinline__ float bf2f(short s) {
  return __uint_as_float(((unsigned)(ushort)s) << 16);
}

__device__ __forceinline__ void gload_lds16(const void* g, void* l) {
  __builtin_amdgcn_global_load_lds(
      (const __attribute__((address_space(1))) unsigned int*)g,
      (__attribute__((address_space(3))) unsigned int*)l, 16, 0, 0);
}

#define VMW(N) do { asm volatile("s_waitcnt vmcnt(" #N ")" ::: "memory"); \
                    __builtin_amdgcn_sched_barrier(0); } while (0)
#define BARR() do { __builtin_amdgcn_s_barrier(); \
                    __builtin_amdgcn_sched_barrier(0); } while (0)

// ---------------------------------------------------------------------------
// fp32 -> bf16 conversion
// ---------------------------------------------------------------------------
__global__ __launch_bounds__(256) void k_cvt(const float* __restrict__ in,
                                             ushort* __restrict__ out, int n4) {
  int i = blockIdx.x * 256 + threadIdx.x;
  if (i < n4) {
    float4 v = ((const float4*)in)[i];
    ushort4 o;
    o.x = rnbf(v.x); o.y = rnbf(v.y); o.z = rnbf(v.z); o.w = rnbf(v.w);
    ((ushort4*)out)[i] = o;
  }
}

// ---------------------------------------------------------------------------
// Kernel 1: qkv = x @ w_attn^T — deep-pipelined counted-vmcnt MFMA GEMM.
// BM=128, BN=256, BK=64, 8 waves (2M x 4N), grid 64x12 = 768 blocks.
// LDS: A slots 3 x [128][64] (t mod 3), B slots [parity][khalf] x [256][32].
// 2 phases/tile; stages prefetched 2-3 phases ahead; vmcnt(6)/(4) steady.
// Epilogue: phi, q/k row-major stores, z fused, kT/vT via LDS transpose.
// ---------------------------------------------------------------------------
#define ABASE(sl) ((sl) * 8192)
#define BBASE(p_, kh_) (24576 + ((p_) * 2 + (kh_)) * 8192)

#define STAGE_A(sl, tt) { \
  const ushort* s_ = Ag + (size_t)sArow * 1024 + (tt) * 64 + sAcol; \
  gload_lds16(s_, &lds[ABASE(sl) + tid * 8]); \
  gload_lds16(s_ + 64 * 1024, &lds[ABASE(sl) + tid * 8 + 4096]); }

#define STAGE_B(p_, kh_, tt) { \
  const ushort* s_ = Bg + (size_t)sBrow * 1024 + (tt) * 64 + (kh_) * 32 + sBcol; \
  gload_lds16(s_, &lds[BBASE(p_, kh_) + tid * 8]); \
  gload_lds16(s_ + (size_t)128 * 1024, &lds[BBASE(p_, kh_) + tid * 8 + 4096]); }

#define LOADA4(sl, kb_) \
  a0 = *(const bf16x8*)&lds[ABASE(sl) + (aRow + 0)  * 64 + (kb_)]; \
  a1 = *(const bf16x8*)&lds[ABASE(sl) + (aRow + 16) * 64 + (kb_)]; \
  a2 = *(const bf16x8*)&lds[ABASE(sl) + (aRow + 32) * 64 + (kb_)]; \
  a3 = *(const bf16x8*)&lds[ABASE(sl) + (aRow + 48) * 64 + (kb_)];

#define LOADB4(p_, kh_) { \
  const int bb_ = BBASE(p_, kh_) + bRow * 32 + bXor; \
  b0 = *(const bf16x8*)&lds[bb_]; \
  b1 = *(const bf16x8*)&lds[bb_ + 16 * 32]; \
  b2 = *(const bf16x8*)&lds[bb_ + 32 * 32]; \
  b3 = *(const bf16x8*)&lds[bb_ + 48 * 32]; }

#define MM(i, j, A_, B_) \
  acc[i][j] = __builtin_amdgcn_mfma_f32_16x16x32_bf16(A_, B_, acc[i][j], 0, 0, 0)
#define MFMA16() do { __builtin_amdgcn_s_setprio(1); \
  MM(0,0,a0,b0); MM(0,1,a0,b1); MM(0,2,a0,b2); MM(0,3,a0,b3); \
  MM(1,0,a1,b0); MM(1,1,a1,b1); MM(1,2,a1,b2); MM(1,3,a1,b3); \
  MM(2,0,a2,b0); MM(2,1,a2,b1); MM(2,2,a2,b2); MM(2,3,a2,b3); \
  MM(3,0,a3,b0); MM(3,1,a3,b1); MM(3,2,a3,b2); MM(3,3,a3,b3); \
  __builtin_amdgcn_s_setprio(0); } while (0)

__global__ __launch_bounds__(512, 1) void k_qkv2(
    const ushort* __restrict__ xb, const ushort* __restrict__ wab,
    ushort* __restrict__ qg, ushort* __restrict__ kg,
    ushort* __restrict__ ktg, ushort* __restrict__ vtg,
    float* __restrict__ zp) {
  extern __shared__ ushort lds[];
  int wg = blockIdx.x;
  wg = (wg & 7) * 96 + (wg >> 3);          // XCD-bijective (768 = 8*96)
  const int bm = wg & 63, bn = wg >> 6;    // 64 x 12
  const int tid = threadIdx.x;
  const int wv = tid >> 6, l = tid & 63;
  const int wm = wv >> 2, wn = wv & 3;
  const ushort* Ag = xb + (size_t)bm * 128 * 1024;
  const ushort* Bg = wab + (size_t)bn * 256 * 1024;
  // staging (pre-swizzled source cols; LDS linear per G21)
  const int sArow = tid >> 3;
  const int sAcol = ((tid & 7) ^ ((tid >> 3) & 7)) * 8;
  const int sBrow = tid >> 2;
  const int sBcol = ((tid & 3) ^ ((tid >> 3) & 3)) * 8;
  // fragment read bases (swizzled)
  const int c16 = l & 15, g4 = l >> 4;
  const int aRow = wm * 64 + c16;
  const int kblk0 = ((0 + g4) ^ (l & 7)) * 8;
  const int kblk1 = ((4 + g4) ^ (l & 7)) * 8;
  const int bRow = wn * 64 + c16;
  const int bXor = (g4 ^ ((l >> 1) & 3)) * 8;

  f32x4 acc[4][4] = {};

  // prologue stage order: A(0), B_k0(0), A(1), B_k1(0), B_k0(1)
  STAGE_A(0, 0);
  STAGE_B(0, 0, 0);
  STAGE_A(1, 1);
  STAGE_B(0, 1, 0);
  STAGE_B(1, 0, 1);

  int sl = 0;
  for (int t = 0; t < NKT_ - 2; ++t) {
    const int p_ = t & 1;
    const int slN = sl ? sl - 1 : 2;  // (sl+2)%3
    VMW(6); BARR();
    bf16x8 a0, a1, a2, a3, b0, b1, b2, b3;
    LOADB4(p_, 0); LOADA4(sl, kblk0);
    STAGE_A(slN, t + 2);
    STAGE_B(p_ ^ 1, 1, t + 1);
    MFMA16();
    VMW(4); BARR();
    LOADB4(p_, 1); LOADA4(sl, kblk1);
    STAGE_B(p_, 0, t + 2);
    MFMA16();
    sl = (sl == 2) ? 0 : sl + 1;
  }
  {  // t = 14, slot 2, parity 0
    VMW(6); BARR();
    bf16x8 a0, a1, a2, a3, b0, b1, b2, b3;
    LOADB4(0, 0); LOADA4(2, kblk0);
    STAGE_B(1, 1, 15);
    MFMA16();
    VMW(4); BARR();
    LOADB4(0, 1); LOADA4(2, kblk1);
    MFMA16();
  }
  {  // t = 15, slot 0, parity 1
    VMW(2); BARR();
    bf16x8 a0, a1, a2, a3, b0, b1, b2, b3;
    LOADB4(1, 0); LOADA4(0, kblk0);
    MFMA16();
    VMW(0); BARR();
    LOADB4(1, 1); LOADA4(0, kblk1);
    MFMA16();
  }

  // ---- epilogue ----
  BARR();  // all LDS reads done; safe to reuse for transpose buffers
  const int colbase = bn * 256 + wn * 64;
  const int which = colbase >> 10;
  const int h = (colbase & 1023) >> 6;
  const int rowbase = bm * 128 + wm * 64;
  const int bidx = rowbase >> 11;
  const int tbase = rowbase & 2047;
  const size_t bh = (size_t)(bidx * 16 + h);
  ushort* wlds = &lds[wv * 4096];  // per-wave 64d x 64t transpose tile
  float zpart[4] = {0.f, 0.f, 0.f, 0.f};
#pragma unroll
  for (int mf = 0; mf < 4; ++mf) {
#pragma unroll
    for (int nf = 0; nf < 4; ++nf) {
      float o[4];
#pragma unroll
      for (int j = 0; j < 4; ++j) {
        float u = acc[mf][nf][j];
        o[j] = (which < 2) ? ((u > 0.f) ? u + 1.f : expf(u)) : u;  // elu+1
      }
      const int d = nf * 16 + c16;
      if (which == 1) zpart[nf] += o[0] + o[1] + o[2] + o[3];
      if (which <= 1) {
        ushort* dst = (which == 0) ? qg : kg;
        const size_t rb = (bh * 2048 + tbase + mf * 16 + g4 * 4) * 64 + d;
#pragma unroll
        for (int j = 0; j < 4; ++j) dst[rb + (size_t)j * 64] = rnbf(o[j]);
      }
      if (which >= 1) {
        const int tb = (mf * 4 + g4) ^ ((d & 3) << 1);
        ushort4 pk;
        pk.x = rnbf(o[0]); pk.y = rnbf(o[1]); pk.z = rnbf(o[2]); pk.w = rnbf(o[3]);
        *(ushort4*)&wlds[d * 64 + tb * 4] = pk;
      }
    }
  }
  if (which == 1) {
    const int cc = tbase >> 7;
#pragma unroll
    for (int nf = 0; nf < 4; ++nf) {
      float zz = zpart[nf];
      zz += __shfl_xor(zz, 16);
      zz += __shfl_xor(zz, 32);
      if (l < 16) zp[((bh * NC_ + cc) * 2 + wm) * 64 + nf * 16 + l] = zz;
    }
  }
  if (which >= 1) {
    asm volatile("s_waitcnt lgkmcnt(0)" ::: "memory");
    __builtin_amdgcn_sched_barrier(0);
    ushort* tg = (which == 1) ? ktg : vtg;
#pragma unroll
    for (int it = 0; it < 8; ++it) {
      const int d = it * 8 + (l >> 3);
      const int t0 = (l & 7) * 8;
      const int blk = ((l & 7) * 2) ^ ((d & 3) << 1);
      bf16x8 vv_ = *(const bf16x8*)&wlds[d * 64 + blk * 4];
      *(bf16x8*)&tg[(bh * 64 + d) * 2048 + tbase + t0] = vv_;
    }
  }
}

// ---------------------------------------------------------------------------
// bf16 MFMA GEMM core (m97-style), used by k_proj
// ---------------------------------------------------------------------------
__device__ __forceinline__ void mfma_gemm(const ushort* __restrict__ Ag,
                                          const ushort* __restrict__ Bg,
                                          ushort* As, ushort* Bs,
                                          f32x4 acc[4][4]) {
  const int tid = threadIdx.x;
  const int w = tid >> 6, l = tid & 63;
  const int wr = (w >> 1) * 64, wc = (w & 1) * 64;
  const int g8 = (l >> 4) * 8, r16 = l & 15;
  const int srow = l >> 2;
  const int scol = (((l & 3) ^ (srow & 3)) * 8);
  const int r0 = w * 32;
  const int xo = g8 ^ ((r16 & 3) << 3);

  for (int kb = 0; kb < 1024; kb += 32) {
    gload_lds16(Ag + (size_t)(r0 + srow) * 1024 + kb + scol, &As[r0 * 32]);
    gload_lds16(Ag + (size_t)(r0 + 16 + srow) * 1024 + kb + scol, &As[(r0 + 16) * 32]);
    gload_lds16(Bg + (size_t)(r0 + srow) * 1024 + kb + scol, &Bs[r0 * 32]);
    gload_lds16(Bg + (size_t)(r0 + 16 + srow) * 1024 + kb + scol, &Bs[(r0 + 16) * 32]);
    __syncthreads();
    bf16x8 af[4], bfr[4];
#pragma unroll
    for (int m = 0; m < 4; ++m)
      af[m] = *(const bf16x8*)&As[(wr + m * 16 + r16) * 32 + xo];
#pragma unroll
    for (int n = 0; n < 4; ++n)
      bfr[n] = *(const bf16x8*)&Bs[(wc + n * 16 + r16) * 32 + xo];
#pragma unroll
    for (int m = 0; m < 4; ++m)
#pragma unroll
      for (int n = 0; n < 4; ++n)
        acc[m][n] = __builtin_amdgcn_mfma_f32_16x16x32_bf16(af[m], bfr[n],
                                                            acc[m][n], 0, 0, 0);
    __syncthreads();
  }
}

// ---------------------------------------------------------------------------
// Kernel 2 (MFMA): per-chunk  ST[e][d] = sum_t v[t][e] k[t][d]  (fp32 out)
// ---------------------------------------------------------------------------
__global__ __launch_bounds__(256) void k_stats(const ushort* __restrict__ ktg,
                                               const ushort* __restrict__ vtg,
                                               float* __restrict__ Sc) {
  __shared__ __align__(16) ushort kT_s[64 * 128], vT_s[64 * 128];
  const int blk = blockIdx.x;
  const int bh = blk >> 4, c = blk & 15;
  const int tid = threadIdx.x;
  const int w = tid >> 6, l = tid & 63;
  const ushort* ktb = ktg + (size_t)bh * D_ * T_ + c * CHUNK_;
  const ushort* vtb = vtg + (size_t)bh * D_ * T_ + c * CHUNK_;
#pragma unroll
  for (int s2 = 0; s2 < 4; ++s2) {
    const int seg = w * 4 + s2;
    const int row = seg * 4 + (l >> 4);
    const int sb = ((l & 15) ^ (row & 7)) * 8;
    gload_lds16(ktb + (size_t)row * T_ + sb, &kT_s[seg * 512]);
    gload_lds16(vtb + (size_t)row * T_ + sb, &vT_s[seg * 512]);
  }
  __syncthreads();
  const int wr = w >> 1, wc = w & 1;
  f32x4 acc[2][2] = {};
#pragma unroll
  for (int kt = 0; kt < 4; ++kt) {
    const int g = kt * 32 + (l >> 4) * 8;
    bf16x8 av[2], bk[2];
#pragma unroll
    for (int rt = 0; rt < 2; ++rt) {
      const int e = wr * 32 + rt * 16 + (l & 15);
      av[rt] = *(const bf16x8*)&vT_s[e * 128 + (g ^ ((e & 7) << 3))];
    }
#pragma unroll
    for (int ct = 0; ct < 2; ++ct) {
      const int d = wc * 32 + ct * 16 + (l & 15);
      bk[ct] = *(const bf16x8*)&kT_s[d * 128 + (g ^ ((d & 7) << 3))];
    }
#pragma unroll
    for (int rt = 0; rt < 2; ++rt)
#pragma unroll
      for (int ct = 0; ct < 2; ++ct)
        acc[rt][ct] = __builtin_amdgcn_mfma_f32_16x16x32_bf16(av[rt], bk[ct],
                                                              acc[rt][ct], 0, 0, 0);
  }
  float* So = Sc + (size_t)blk * 4096;
#pragma unroll
  for (int rt = 0; rt < 2; ++rt)
#pragma unroll
    for (int ct = 0; ct < 2; ++ct)
#pragma unroll
      for (int jj = 0; jj < 4; ++jj)
        So[(wr * 32 + rt * 16 + (l >> 4) * 4 + jj) * 64 + wc * 32 + ct * 16 + (l & 15)] =
            acc[rt][ct][jj];
}

// ---------------------------------------------------------------------------
// Kernel 3: exclusive prefix over 16 chunks; S fp32 -> bf16 ST; z halves -> z
// ---------------------------------------------------------------------------
__global__ __launch_bounds__(256) void k_prefix(const float* __restrict__ Sc,
                                                ushort* __restrict__ STb,
                                                const float* __restrict__ zp,
                                                float* __restrict__ zout) {
  const int bh = blockIdx.x;
  const int tid = threadIdx.x;
  const float4* Sb = (const float4*)(Sc + (size_t)bh * NC_ * 4096);
  ushort4* Ob = (ushort4*)(STb + (size_t)bh * NC_ * 4096);
  float4 acc[4];
#pragma unroll
  for (int j = 0; j < 4; ++j) acc[j] = make_float4(0.f, 0.f, 0.f, 0.f);
  for (int c = 0; c < NC_; ++c) {
#pragma unroll
    for (int j = 0; j < 4; ++j) {
      const int idx = c * 1024 + tid + 256 * j;
      float4 tv = Sb[idx];
      ushort4 o;
      o.x = rnbf(acc[j].x); o.y = rnbf(acc[j].y);
      o.z = rnbf(acc[j].z); o.w = rnbf(acc[j].w);
      Ob[idx] = o;
      acc[j].x += tv.x; acc[j].y += tv.y; acc[j].z += tv.z; acc[j].w += tv.w;
    }
  }
  if (tid < 16) {
    const float4* zpb = (const float4*)(zp + (size_t)bh * NC_ * 128);
    float4* zob = (float4*)(zout + (size_t)bh * NC_ * 64);
    float4 za = make_float4(0.f, 0.f, 0.f, 0.f);
    for (int c = 0; c < NC_; ++c) {
      float4 t0 = zpb[c * 32 + tid];
      float4 t1 = zpb[c * 32 + 16 + tid];
      zob[c * 16 + tid] = za;
      za.x += t0.x + t1.x; za.y += t0.y + t1.y;
      za.z += t0.z + t1.z; za.w += t0.w + t1.w;
    }
  }
}

// ---------------------------------------------------------------------------
// Kernel 4 (MFMA): per-chunk output -> y bf16 [B,T,H,D]
// ---------------------------------------------------------------------------
__global__ __launch_bounds__(512, 4) void k_out(
    const ushort* __restrict__ qg, const ushort* __restrict__ kg,
    const ushort* __restrict__ vtg, const ushort* __restrict__ STb,
    const float* __restrict__ zg, ushort* __restrict__ yb) {
  __shared__ __align__(16) ushort k_s[128 * 64];
  __shared__ __align__(16) ushort vT_s[64 * 128];
  __shared__ __align__(16) ushort ST_s[64 * 64];
  __shared__ __align__(16) ushort P_s[128 * 128];
  __shared__ float z_s[64];
  __shared__ float dinter_s[128];
  const int blk = blockIdx.x;
  const int bh = blk >> 4, c = blk & 15;
  const int tid = threadIdx.x;
  const int w = tid >> 6, l = tid & 63;

  const ushort* kbase = kg + ((size_t)bh * T_ + c * CHUNK_) * D_;
  const ushort* vbase = vtg + (size_t)bh * D_ * T_ + c * CHUNK_;
  const ushort* sbase = STb + ((size_t)bh * NC_ + c) * 4096;
  {
    int seg = w, row = seg * 8 + (l >> 3);
    gload_lds16(kbase + (size_t)row * 64 + ((l & 7) ^ (row & 7)) * 8, &k_s[seg * 512]);
    seg = w + 8; row = seg * 8 + (l >> 3);
    gload_lds16(kbase + (size_t)row * 64 + ((l & 7) ^ (row & 7)) * 8, &k_s[seg * 512]);
  }
  {
    int seg = w, row = seg * 4 + (l >> 4);
    gload_lds16(vbase + (size_t)row * T_ + ((l & 15) ^ (row & 7)) * 8, &vT_s[seg * 512]);
    seg = w + 8; row = seg * 4 + (l >> 4);
    gload_lds16(vbase + (size_t)row * T_ + ((l & 15) ^ (row & 7)) * 8, &vT_s[seg * 512]);
  }
  {
    const int seg = w, row = seg * 8 + (l >> 3);
    gload_lds16(sbase + (size_t)row * 64 + ((l & 7) ^ (row & 7)) * 8, &ST_s[seg * 512]);
  }
  if (tid < 64) z_s[tid] = zg[((size_t)bh * NC_ + c) * 64 + tid];
  const int arow = w * 16 + (l & 15);
  const ushort* qrow = qg + ((size_t)bh * T_ + c * CHUNK_ + arow) * D_ + (l >> 4) * 8;
  bf16x8 qf0 = *(const bf16x8*)(qrow);
  bf16x8 qf1 = *(const bf16x8*)(qrow + 32);
  __syncthreads();

  f32x4 sc[8] = {};
#pragma unroll
  for (int jt = 0; jt < 8; ++jt) {
    const int j = jt * 16 + (l & 15);
    const int sw = (j & 7) << 3, g = (l >> 4) * 8;
    bf16x8 b0 = *(const bf16x8*)&k_s[j * 64 + (g ^ sw)];
    bf16x8 b1 = *(const bf16x8*)&k_s[j * 64 + ((g + 32) ^ sw)];
    sc[jt] = __builtin_amdgcn_mfma_f32_16x16x32_bf16(qf0, b0, sc[jt], 0, 0, 0);
    sc[jt] = __builtin_amdgcn_mfma_f32_16x16x32_bf16(qf1, b1, sc[jt], 0, 0, 0);
  }
  const int crow0 = w * 16 + (l >> 4) * 4;
  float rsum[4] = {0.f, 0.f, 0.f, 0.f};
#pragma unroll
  for (int jt = 0; jt < 8; ++jt) {
    const int j = jt * 16 + (l & 15);
#pragma unroll
    for (int jj = 0; jj < 4; ++jj) {
      const int i = crow0 + jj;
      float s = (j <= i) ? sc[jt][jj] : 0.f;
      rsum[jj] += s;
      P_s[i * 128 + (j ^ ((i & 7) << 3))] = rnbf(s);
    }
  }
  float di = 0.f;
#pragma unroll
  for (int jj = 0; jj < 8; ++jj) {
    di = fmaf(bf2f(qf0[jj]), z_s[(l >> 4) * 8 + jj], di);
    di = fmaf(bf2f(qf1[jj]), z_s[32 + (l >> 4) * 8 + jj], di);
  }
  di += __shfl_xor(di, 16);
  di += __shfl_xor(di, 32);
  if (l < 16) dinter_s[w * 16 + l] = di;
#pragma unroll
  for (int jj = 0; jj < 4; ++jj) {
    float r = rsum[jj];
    r += __shfl_xor(r, 1); r += __shfl_xor(r, 2);
    r += __shfl_xor(r, 4); r += __shfl_xor(r, 8);
    rsum[jj] = r;
  }
  __syncthreads();

  f32x4 acc2[4] = {};
#pragma unroll
  for (int et = 0; et < 4; ++et) {
    const int e = et * 16 + (l & 15);
    const int sw = (e & 7) << 3, g = (l >> 4) * 8;
    bf16x8 s0 = *(const bf16x8*)&ST_s[e * 64 + (g ^ sw)];
    bf16x8 s1 = *(const bf16x8*)&ST_s[e * 64 + ((g + 32) ^ sw)];
    acc2[et] = __builtin_amdgcn_mfma_f32_16x16x32_bf16(qf0, s0, acc2[et], 0, 0, 0);
    acc2[et] = __builtin_amdgcn_mfma_f32_16x16x32_bf16(qf1, s1, acc2[et], 0, 0, 0);
  }
  const int prow = w * 16 + (l & 15);
  const int psw = (prow & 7) << 3;
#pragma unroll
  for (int jkt = 0; jkt < 4; ++jkt) {
    bf16x8 pa = *(const bf16x8*)&P_s[prow * 128 + ((jkt * 32 + (l >> 4) * 8) ^ psw)];
#pragma unroll
    for (int et = 0; et < 4; ++et) {
      const int e = et * 16 + (l & 15);
      bf16x8 bv = *(const bf16x8*)&vT_s[e * 128 +
                                        ((jkt * 32 + (l >> 4) * 8) ^ ((e & 7) << 3))];
      acc2[et] = __builtin_amdgcn_mfma_f32_16x16x32_bf16(pa, bv, acc2[et], 0, 0, 0);
    }
  }
  float inv[4];
#pragma unroll
  for (int jj = 0; jj < 4; ++jj)
    inv[jj] = 1.0f / (rsum[jj] + dinter_s[crow0 + jj] + 1e-6f);
  const int b = bh >> 4, h = bh & 15;
#pragma unroll
  for (int et = 0; et < 4; ++et) {
    const int d = et * 16 + (l & 15);
#pragma unroll
    for (int jj = 0; jj < 4; ++jj) {
      const int t = c * CHUNK_ + crow0 + jj;
      yb[((size_t)(b * T_ + t) * H_ + h) * D_ + d] = rnbf(acc2[et][jj] * inv[jj]);
    }
  }
}

// ---------------------------------------------------------------------------
// Kernel 5: out = y @ w_proj^T (bf16 MFMA), fp32 out
// ---------------------------------------------------------------------------
__global__ __launch_bounds__(256) void k_proj(const ushort* __restrict__ yb,
                                              const ushort* __restrict__ wpb,
                                              float* __restrict__ out) {
  __shared__ __align__(16) ushort As[4096], Bs[4096];
  f32x4 acc[4][4] = {};
  const int bm = blockIdx.x, bn = blockIdx.y;
  mfma_gemm(yb + (size_t)bm * 128 * 1024, wpb + (size_t)bn * 128 * 1024, As, Bs, acc);
  const int tid = threadIdx.x;
  const int w = tid >> 6, l = tid & 63;
  const int wr = (w >> 1) * 64, wc = (w & 1) * 64;
  const int rg4 = (l >> 4) * 4, c16 = l & 15;
#pragma unroll
  for (int m = 0; m < 4; ++m)
#pragma unroll
    for (int n = 0; n < 4; ++n)
#pragma unroll
      for (int j = 0; j < 4; ++j) {
        const int row = bm * 128 + wr + m * 16 + rg4 + j;
        const int col = bn * 128 + wc + n * 16 + c16;
        out[(size_t)row * 1024 + col] = acc[m][n][j];
      }
}

// ---------------------------------------------------------------------------
extern "C" void kernel_launch(void* const* d_in, const int* in_sizes, int n_in,
                              void* d_out, int out_size, void* d_ws, size_t ws_size,
                              hipStream_t stream) {
  const float* x = (const float*)d_in[0];
  const float* w_attn = (const float*)d_in[1];
  const float* w_proj = (const float*)d_in[2];
  float* out = (float*)d_out;

  ushort* xb = (ushort*)d_ws;                        // [8192,1024]
  ushort* wab = xb + (size_t)M_ * E_;                // [3072,1024]
  ushort* wpb = wab + (size_t)3 * E_ * E_;           // [1024,1024]
  ushort* qb = wpb + (size_t)E_ * E_;                // [bh][t][d]
  ushort* kbm = qb + (size_t)M_ * E_;                // [bh][t][d]
  ushort* kT = kbm + (size_t)M_ * E_;                // [bh][d][t]
  ushort* vT = kT + (size_t)M_ * E_;                 // [bh][d][t]
  ushort* yb = vT + (size_t)M_ * E_;                 // [B,T,H,D]
  ushort* STb = yb + (size_t)M_ * E_;                // [bh][c][e][d] bf16
  float* Schunk = (float*)(STb + (size_t)BH_ * NC_ * 4096);  // fp32
  float* zpart = Schunk + (size_t)BH_ * NC_ * 4096;  // [bh][c][2][64]
  float* zout = zpart + (size_t)BH_ * NC_ * 2 * 64;  // [bh][c][64]

  k_cvt<<<8192, 256, 0, stream>>>(x, xb, (M_ * E_) / 4);
  k_cvt<<<3072, 256, 0, stream>>>(w_attn, wab, (3 * E_ * E_) / 4);
  k_cvt<<<1024, 256, 0, stream>>>(w_proj, wpb, (E_ * E_) / 4);

  hipFuncSetAttribute((const void*)k_qkv2,
                      hipFuncAttributeMaxDynamicSharedMemorySize, 114688);
  k_qkv2<<<768, 512, 114688, stream>>>(xb, wab, qb, kbm, kT, vT, zpart);

  k_stats<<<1024, 256, 0, stream>>>(kT, vT, Schunk);
  k_prefix<<<64, 256, 0, stream>>>(Schunk, STb, zpart, zout);
  k_out<<<1024, 512, 0, stream>>>(qb, kbm, vT, STb, zout, yb);
  k_proj<<<dim3(64, 8), 256, 0, stream>>>(yb, wpb, out);
}

// Round 5
// 149.560 us; speedup vs baseline: 6.7745x; 1.1235x over previous
//
#include <hip/hip_runtime.h>
#include <math.h>

#define B_ 4
#define T_ 2048
#define E_ 1024
#define H_ 16
#define D_ 64
#define CHUNK_ 128
#define NC_ 16
#define BH_ (B_ * H_)   // 64
#define M_ (B_ * T_)    // 8192

typedef __attribute__((ext_vector_type(8))) short bf16x8;
typedef __attribute__((ext_vector_type(4))) float f32x4;

__device__ __forceinline__ ushort rnbf(float f) {
  unsigned u = __float_as_uint(f);
  unsigned r = (u + 0x7FFFu + ((u >> 16) & 1u)) >> 16;
  return (ushort)r;
}

__device__ __forceinline__ float bf2f(short s) {
  return __uint_as_float(((unsigned)(ushort)s) << 16);
}

__device__ __forceinline__ void gload_lds16(const void* g, void* l) {
  __builtin_amdgcn_global_load_lds(
      (const __attribute__((address_space(1))) unsigned int*)g,
      (__attribute__((address_space(3))) unsigned int*)l, 16, 0, 0);
}

#define VMW(N) do { asm volatile("s_waitcnt vmcnt(" #N ")" ::: "memory"); \
                    __builtin_amdgcn_sched_barrier(0); } while (0)
#define BARR() do { __builtin_amdgcn_s_barrier(); \
                    __builtin_amdgcn_sched_barrier(0); } while (0)

// ---------------------------------------------------------------------------
// fp32 -> bf16 conversion
// ---------------------------------------------------------------------------
__global__ __launch_bounds__(256) void k_cvt(const float* __restrict__ in,
                                             ushort* __restrict__ out, int n4) {
  int i = blockIdx.x * 256 + threadIdx.x;
  if (i < n4) {
    float4 v = ((const float4*)in)[i];
    ushort4 o;
    o.x = rnbf(v.x); o.y = rnbf(v.y); o.z = rnbf(v.z); o.w = rnbf(v.w);
    ((ushort4*)out)[i] = o;
  }
}

// ---------------------------------------------------------------------------
// Pipelined MFMA GEMM core: C 128x256 tile = A[128xK] x B[256xK]^T, K=1024.
// 8 waves (2M x 4N), per-wave 64x64 = acc[4][4]. BK=32 slabs, 3-deep
// rotation (72 KB LDS -> 2 blocks/CU). Per phase: VMW(3) (wait = load
// issued 2 phases prior), barrier, 8 ds_read_b128 (chunk-XOR swizzled,
// conflict-free), stage slot t+2, 16 MFMA (setprio-wrapped).
// ---------------------------------------------------------------------------
#define STG(sl_, tt_) { \
  gload_lds16(Asrc + (tt_) * 32, &lds[(sl_) * 4096 + tid * 8]); \
  gload_lds16(Bsrc0 + (tt_) * 32, &lds[12288 + (sl_) * 8192 + tid * 8]); \
  gload_lds16(Bsrc1 + (tt_) * 32, &lds[12288 + (sl_) * 8192 + 4096 + tid * 8]); }

#define LDFRAGS(sl_) \
  const ushort* pa = &lds[(sl_) * 4096 + aOff]; \
  a0 = *(const bf16x8*)pa;          a1 = *(const bf16x8*)(pa + 512); \
  a2 = *(const bf16x8*)(pa + 1024); a3 = *(const bf16x8*)(pa + 1536); \
  const ushort* pb = &lds[12288 + (sl_) * 8192 + bOff]; \
  b0 = *(const bf16x8*)pb;          b1 = *(const bf16x8*)(pb + 512); \
  b2 = *(const bf16x8*)(pb + 1024); b3 = *(const bf16x8*)(pb + 1536);

#define MM(i, j, A_, B_) \
  acc[i][j] = __builtin_amdgcn_mfma_f32_16x16x32_bf16(A_, B_, acc[i][j], 0, 0, 0)
#define MFMA16() do { __builtin_amdgcn_s_setprio(1); \
  MM(0,0,a0,b0); MM(0,1,a0,b1); MM(0,2,a0,b2); MM(0,3,a0,b3); \
  MM(1,0,a1,b0); MM(1,1,a1,b1); MM(1,2,a1,b2); MM(1,3,a1,b3); \
  MM(2,0,a2,b0); MM(2,1,a2,b1); MM(2,2,a2,b2); MM(2,3,a2,b3); \
  MM(3,0,a3,b0); MM(3,1,a3,b1); MM(3,2,a3,b2); MM(3,3,a3,b3); \
  __builtin_amdgcn_s_setprio(0); } while (0)

__device__ __forceinline__ void pipe_gemm(const ushort* __restrict__ Ag,
                                          const ushort* __restrict__ Bg,
                                          ushort* lds, f32x4 acc[4][4]) {
  const int tid = threadIdx.x;
  const int l = tid & 63, wv = tid >> 6;
  const int wm = wv >> 2, wn = wv & 3;
  const int c16 = l & 15, g4 = l >> 4;
  // staging: thread -> (row = tid>>2, LDS chunk = tid&3); source chunk is
  // inverse-swizzled so LDS(row,c) holds global chunk c ^ ((row>>1)&3)
  const int gch = (tid & 3) ^ ((tid >> 3) & 3);
  const ushort* Asrc = Ag + (size_t)(tid >> 2) * 1024 + gch * 8;
  const ushort* Bsrc0 = Bg + (size_t)(tid >> 2) * 1024 + gch * 8;
  const ushort* Bsrc1 = Bsrc0 + (size_t)128 * 1024;
  // fragment reads: want global chunk g4 -> read position g4 ^ ((row>>1)&3)
  const int xq = (c16 >> 1) & 3;
  const int aOff = (wm * 64 + c16) * 32 + ((g4 ^ xq) << 3);
  const int bOff = (wn * 64 + c16) * 32 + ((g4 ^ xq) << 3);

  STG(0, 0);
  STG(1, 1);
  int sl = 0;
#pragma unroll 3
  for (int t = 0; t < 30; ++t) {
    const int slN = sl ? sl - 1 : 2;  // (sl+2)%3
    VMW(3); BARR();
    bf16x8 a0, a1, a2, a3, b0, b1, b2, b3;
    LDFRAGS(sl);
    STG(slN, t + 2);
    MFMA16();
    sl = (sl == 2) ? 0 : sl + 1;
  }
  {  // t=30, slab 0
    VMW(3); BARR();
    bf16x8 a0, a1, a2, a3, b0, b1, b2, b3;
    LDFRAGS(0);
    MFMA16();
  }
  {  // t=31, slab 1
    VMW(0); BARR();
    bf16x8 a0, a1, a2, a3, b0, b1, b2, b3;
    LDFRAGS(1);
    MFMA16();
  }
}

// ---------------------------------------------------------------------------
// Kernel 1: qkv = x @ w_attn^T; phi on q,k; q/k row-major, kT/vT transposed
// (via per-wave LDS transpose), z chunk-partials fused. grid 768 = 3.0 rounds.
// ---------------------------------------------------------------------------
__global__ __launch_bounds__(512, 4) void k_qkv2(
    const ushort* __restrict__ xb, const ushort* __restrict__ wab,
    ushort* __restrict__ qg, ushort* __restrict__ kg,
    ushort* __restrict__ ktg, ushort* __restrict__ vtg,
    float* __restrict__ zp) {
  extern __shared__ ushort lds[];
  int wg = blockIdx.x;
  wg = (wg & 7) * 96 + (wg >> 3);          // XCD-bijective (768 = 8*96)
  const int bm = wg & 63, bn = wg >> 6;    // 64 x 12
  const int tid = threadIdx.x;
  const int wv = tid >> 6, l = tid & 63;
  const int wm = wv >> 2, wn = wv & 3;
  const int c16 = l & 15, g4 = l >> 4;

  f32x4 acc[4][4] = {};
  pipe_gemm(xb + (size_t)bm * 128 * 1024, wab + (size_t)bn * 256 * 1024, lds, acc);

  // ---- epilogue ----
  BARR();  // all LDS reads done; safe to reuse for transpose buffers
  const int colbase = bn * 256 + wn * 64;
  const int which = colbase >> 10;
  const int h = (colbase & 1023) >> 6;
  const int rowbase = bm * 128 + wm * 64;
  const int bidx = rowbase >> 11;
  const int tbase = rowbase & 2047;
  const size_t bh = (size_t)(bidx * 16 + h);
  ushort* wlds = &lds[wv * 4096];  // per-wave 64d x 64t transpose tile
  float zpart[4] = {0.f, 0.f, 0.f, 0.f};
#pragma unroll
  for (int mf = 0; mf < 4; ++mf) {
#pragma unroll
    for (int nf = 0; nf < 4; ++nf) {
      float o[4];
#pragma unroll
      for (int j = 0; j < 4; ++j) {
        float u = acc[mf][nf][j];
        o[j] = (which < 2) ? ((u > 0.f) ? u + 1.f : expf(u)) : u;  // elu+1
      }
      const int d = nf * 16 + c16;
      if (which == 1) zpart[nf] += o[0] + o[1] + o[2] + o[3];
      if (which <= 1) {
        ushort* dst = (which == 0) ? qg : kg;
        const size_t rb = (bh * 2048 + tbase + mf * 16 + g4 * 4) * 64 + d;
#pragma unroll
        for (int j = 0; j < 4; ++j) dst[rb + (size_t)j * 64] = rnbf(o[j]);
      }
      if (which >= 1) {
        const int tb = (mf * 4 + g4) ^ ((d & 3) << 1);
        ushort4 pk;
        pk.x = rnbf(o[0]); pk.y = rnbf(o[1]); pk.z = rnbf(o[2]); pk.w = rnbf(o[3]);
        *(ushort4*)&wlds[d * 64 + tb * 4] = pk;
      }
    }
  }
  if (which == 1) {
    const int cc = tbase >> 7;
#pragma unroll
    for (int nf = 0; nf < 4; ++nf) {
      float zz = zpart[nf];
      zz += __shfl_xor(zz, 16);
      zz += __shfl_xor(zz, 32);
      if (l < 16) zp[((bh * NC_ + cc) * 2 + wm) * 64 + nf * 16 + l] = zz;
    }
  }
  if (which >= 1) {
    asm volatile("s_waitcnt lgkmcnt(0)" ::: "memory");
    __builtin_amdgcn_sched_barrier(0);
    ushort* tg = (which == 1) ? ktg : vtg;
#pragma unroll
    for (int it = 0; it < 8; ++it) {
      const int d = it * 8 + (l >> 3);
      const int t0 = (l & 7) * 8;
      const int blk = ((l & 7) * 2) ^ ((d & 3) << 1);
      bf16x8 vv_ = *(const bf16x8*)&wlds[d * 64 + blk * 4];
      *(bf16x8*)&tg[(bh * 64 + d) * 2048 + tbase + t0] = vv_;
    }
  }
}

// ---------------------------------------------------------------------------
// Kernel 5: out = y @ w_proj^T, same pipelined core, fp32 epilogue.
// grid 256 blocks = exactly 1.0 CU-round (2 blocks/CU capable).
// ---------------------------------------------------------------------------
__global__ __launch_bounds__(512, 4) void k_proj2(
    const ushort* __restrict__ yb, const ushort* __restrict__ wpb,
    float* __restrict__ out) {
  extern __shared__ ushort lds[];
  int wg = blockIdx.x;
  wg = (wg & 7) * 32 + (wg >> 3);          // XCD-bijective (256 = 8*32)
  const int bm = wg & 63, bn = wg >> 6;    // 64 x 4
  const int tid = threadIdx.x;
  const int wv = tid >> 6, l = tid & 63;
  const int wm = wv >> 2, wn = wv & 3;
  const int c16 = l & 15, g4 = l >> 4;

  f32x4 acc[4][4] = {};
  pipe_gemm(yb + (size_t)bm * 128 * 1024, wpb + (size_t)bn * 256 * 1024, lds, acc);

  const int rowbase = bm * 128 + wm * 64 + g4 * 4;
  const int colbase = bn * 256 + wn * 64 + c16;
#pragma unroll
  for (int mf = 0; mf < 4; ++mf)
#pragma unroll
    for (int nf = 0; nf < 4; ++nf) {
      const size_t base = (size_t)(rowbase + mf * 16) * 1024 + colbase + nf * 16;
#pragma unroll
      for (int j = 0; j < 4; ++j)
        out[base + (size_t)j * 1024] = acc[mf][nf][j];
    }
}

// ---------------------------------------------------------------------------
// Kernel 2 (MFMA): per-chunk  ST[e][d] = sum_t v[t][e] k[t][d]  (fp32 out)
// ---------------------------------------------------------------------------
__global__ __launch_bounds__(256) void k_stats(const ushort* __restrict__ ktg,
                                               const ushort* __restrict__ vtg,
                                               float* __restrict__ Sc) {
  __shared__ __align__(16) ushort kT_s[64 * 128], vT_s[64 * 128];
  const int blk = blockIdx.x;
  const int bh = blk >> 4, c = blk & 15;
  const int tid = threadIdx.x;
  const int w = tid >> 6, l = tid & 63;
  const ushort* ktb = ktg + (size_t)bh * D_ * T_ + c * CHUNK_;
  const ushort* vtb = vtg + (size_t)bh * D_ * T_ + c * CHUNK_;
#pragma unroll
  for (int s2 = 0; s2 < 4; ++s2) {
    const int seg = w * 4 + s2;
    const int row = seg * 4 + (l >> 4);
    const int sb = ((l & 15) ^ (row & 7)) * 8;
    gload_lds16(ktb + (size_t)row * T_ + sb, &kT_s[seg * 512]);
    gload_lds16(vtb + (size_t)row * T_ + sb, &vT_s[seg * 512]);
  }
  __syncthreads();
  const int wr = w >> 1, wc = w & 1;
  f32x4 acc[2][2] = {};
#pragma unroll
  for (int kt = 0; kt < 4; ++kt) {
    const int g = kt * 32 + (l >> 4) * 8;
    bf16x8 av[2], bk[2];
#pragma unroll
    for (int rt = 0; rt < 2; ++rt) {
      const int e = wr * 32 + rt * 16 + (l & 15);
      av[rt] = *(const bf16x8*)&vT_s[e * 128 + (g ^ ((e & 7) << 3))];
    }
#pragma unroll
    for (int ct = 0; ct < 2; ++ct) {
      const int d = wc * 32 + ct * 16 + (l & 15);
      bk[ct] = *(const bf16x8*)&kT_s[d * 128 + (g ^ ((d & 7) << 3))];
    }
#pragma unroll
    for (int rt = 0; rt < 2; ++rt)
#pragma unroll
      for (int ct = 0; ct < 2; ++ct)
        acc[rt][ct] = __builtin_amdgcn_mfma_f32_16x16x32_bf16(av[rt], bk[ct],
                                                              acc[rt][ct], 0, 0, 0);
  }
  float* So = Sc + (size_t)blk * 4096;
#pragma unroll
  for (int rt = 0; rt < 2; ++rt)
#pragma unroll
    for (int ct = 0; ct < 2; ++ct)
#pragma unroll
      for (int jj = 0; jj < 4; ++jj)
        So[(wr * 32 + rt * 16 + (l >> 4) * 4 + jj) * 64 + wc * 32 + ct * 16 + (l & 15)] =
            acc[rt][ct][jj];
}

// ---------------------------------------------------------------------------
// Kernel 3: exclusive prefix over 16 chunks; S fp32 -> bf16 ST; z halves -> z
// ---------------------------------------------------------------------------
__global__ __launch_bounds__(256) void k_prefix(const float* __restrict__ Sc,
                                                ushort* __restrict__ STb,
                                                const float* __restrict__ zp,
                                                float* __restrict__ zout) {
  const int bh = blockIdx.x;
  const int tid = threadIdx.x;
  const float4* Sb = (const float4*)(Sc + (size_t)bh * NC_ * 4096);
  ushort4* Ob = (ushort4*)(STb + (size_t)bh * NC_ * 4096);
  float4 acc[4];
#pragma unroll
  for (int j = 0; j < 4; ++j) acc[j] = make_float4(0.f, 0.f, 0.f, 0.f);
  for (int c = 0; c < NC_; ++c) {
#pragma unroll
    for (int j = 0; j < 4; ++j) {
      const int idx = c * 1024 + tid + 256 * j;
      float4 tv = Sb[idx];
      ushort4 o;
      o.x = rnbf(acc[j].x); o.y = rnbf(acc[j].y);
      o.z = rnbf(acc[j].z); o.w = rnbf(acc[j].w);
      Ob[idx] = o;
      acc[j].x += tv.x; acc[j].y += tv.y; acc[j].z += tv.z; acc[j].w += tv.w;
    }
  }
  if (tid < 16) {
    const float4* zpb = (const float4*)(zp + (size_t)bh * NC_ * 128);
    float4* zob = (float4*)(zout + (size_t)bh * NC_ * 64);
    float4 za = make_float4(0.f, 0.f, 0.f, 0.f);
    for (int c = 0; c < NC_; ++c) {
      float4 t0 = zpb[c * 32 + tid];
      float4 t1 = zpb[c * 32 + 16 + tid];
      zob[c * 16 + tid] = za;
      za.x += t0.x + t1.x; za.y += t0.y + t1.y;
      za.z += t0.z + t1.z; za.w += t0.w + t1.w;
    }
  }
}

// ---------------------------------------------------------------------------
// Kernel 4 (MFMA): per-chunk output -> y bf16 [B,T,H,D]
// ---------------------------------------------------------------------------
__global__ __launch_bounds__(512, 4) void k_out(
    const ushort* __restrict__ qg, const ushort* __restrict__ kg,
    const ushort* __restrict__ vtg, const ushort* __restrict__ STb,
    const float* __restrict__ zg, ushort* __restrict__ yb) {
  __shared__ __align__(16) ushort k_s[128 * 64];
  __shared__ __align__(16) ushort vT_s[64 * 128];
  __shared__ __align__(16) ushort ST_s[64 * 64];
  __shared__ __align__(16) ushort P_s[128 * 128];
  __shared__ float z_s[64];
  __shared__ float dinter_s[128];
  const int blk = blockIdx.x;
  const int bh = blk >> 4, c = blk & 15;
  const int tid = threadIdx.x;
  const int w = tid >> 6, l = tid & 63;

  const ushort* kbase = kg + ((size_t)bh * T_ + c * CHUNK_) * D_;
  const ushort* vbase = vtg + (size_t)bh * D_ * T_ + c * CHUNK_;
  const ushort* sbase = STb + ((size_t)bh * NC_ + c) * 4096;
  {
    int seg = w, row = seg * 8 + (l >> 3);
    gload_lds16(kbase + (size_t)row * 64 + ((l & 7) ^ (row & 7)) * 8, &k_s[seg * 512]);
    seg = w + 8; row = seg * 8 + (l >> 3);
    gload_lds16(kbase + (size_t)row * 64 + ((l & 7) ^ (row & 7)) * 8, &k_s[seg * 512]);
  }
  {
    int seg = w, row = seg * 4 + (l >> 4);
    gload_lds16(vbase + (size_t)row * T_ + ((l & 15) ^ (row & 7)) * 8, &vT_s[seg * 512]);
    seg = w + 8; row = seg * 4 + (l >> 4);
    gload_lds16(vbase + (size_t)row * T_ + ((l & 15) ^ (row & 7)) * 8, &vT_s[seg * 512]);
  }
  {
    const int seg = w, row = seg * 8 + (l >> 3);
    gload_lds16(sbase + (size_t)row * 64 + ((l & 7) ^ (row & 7)) * 8, &ST_s[seg * 512]);
  }
  if (tid < 64) z_s[tid] = zg[((size_t)bh * NC_ + c) * 64 + tid];
  const int arow = w * 16 + (l & 15);
  const ushort* qrow = qg + ((size_t)bh * T_ + c * CHUNK_ + arow) * D_ + (l >> 4) * 8;
  bf16x8 qf0 = *(const bf16x8*)(qrow);
  bf16x8 qf1 = *(const bf16x8*)(qrow + 32);
  __syncthreads();

  f32x4 sc[8] = {};
#pragma unroll
  for (int jt = 0; jt < 8; ++jt) {
    const int j = jt * 16 + (l & 15);
    const int sw = (j & 7) << 3, g = (l >> 4) * 8;
    bf16x8 b0 = *(const bf16x8*)&k_s[j * 64 + (g ^ sw)];
    bf16x8 b1 = *(const bf16x8*)&k_s[j * 64 + ((g + 32) ^ sw)];
    sc[jt] = __builtin_amdgcn_mfma_f32_16x16x32_bf16(qf0, b0, sc[jt], 0, 0, 0);
    sc[jt] = __builtin_amdgcn_mfma_f32_16x16x32_bf16(qf1, b1, sc[jt], 0, 0, 0);
  }
  const int crow0 = w * 16 + (l >> 4) * 4;
  float rsum[4] = {0.f, 0.f, 0.f, 0.f};
#pragma unroll
  for (int jt = 0; jt < 8; ++jt) {
    const int j = jt * 16 + (l & 15);
#pragma unroll
    for (int jj = 0; jj < 4; ++jj) {
      const int i = crow0 + jj;
      float s = (j <= i) ? sc[jt][jj] : 0.f;
      rsum[jj] += s;
      P_s[i * 128 + (j ^ ((i & 7) << 3))] = rnbf(s);
    }
  }
  float di = 0.f;
#pragma unroll
  for (int jj = 0; jj < 8; ++jj) {
    di = fmaf(bf2f(qf0[jj]), z_s[(l >> 4) * 8 + jj], di);
    di = fmaf(bf2f(qf1[jj]), z_s[32 + (l >> 4) * 8 + jj], di);
  }
  di += __shfl_xor(di, 16);
  di += __shfl_xor(di, 32);
  if (l < 16) dinter_s[w * 16 + l] = di;
#pragma unroll
  for (int jj = 0; jj < 4; ++jj) {
    float r = rsum[jj];
    r += __shfl_xor(r, 1); r += __shfl_xor(r, 2);
    r += __shfl_xor(r, 4); r += __shfl_xor(r, 8);
    rsum[jj] = r;
  }
  __syncthreads();

  f32x4 acc2[4] = {};
#pragma unroll
  for (int et = 0; et < 4; ++et) {
    const int e = et * 16 + (l & 15);
    const int sw = (e & 7) << 3, g = (l >> 4) * 8;
    bf16x8 s0 = *(const bf16x8*)&ST_s[e * 64 + (g ^ sw)];
    bf16x8 s1 = *(const bf16x8*)&ST_s[e * 64 + ((g + 32) ^ sw)];
    acc2[et] = __builtin_amdgcn_mfma_f32_16x16x32_bf16(qf0, s0, acc2[et], 0, 0, 0);
    acc2[et] = __builtin_amdgcn_mfma_f32_16x16x32_bf16(qf1, s1, acc2[et], 0, 0, 0);
  }
  const int prow = w * 16 + (l & 15);
  const int psw = (prow & 7) << 3;
#pragma unroll
  for (int jkt = 0; jkt < 4; ++jkt) {
    bf16x8 pa = *(const bf16x8*)&P_s[prow * 128 + ((jkt * 32 + (l >> 4) * 8) ^ psw)];
#pragma unroll
    for (int et = 0; et < 4; ++et) {
      const int e = et * 16 + (l & 15);
      bf16x8 bv = *(const bf16x8*)&vT_s[e * 128 +
                                        ((jkt * 32 + (l >> 4) * 8) ^ ((e & 7) << 3))];
      acc2[et] = __builtin_amdgcn_mfma_f32_16x16x32_bf16(pa, bv, acc2[et], 0, 0, 0);
    }
  }
  float inv[4];
#pragma unroll
  for (int jj = 0; jj < 4; ++jj)
    inv[jj] = 1.0f / (rsum[jj] + dinter_s[crow0 + jj] + 1e-6f);
  const int b = bh >> 4, h = bh & 15;
#pragma unroll
  for (int et = 0; et < 4; ++et) {
    const int d = et * 16 + (l & 15);
#pragma unroll
    for (int jj = 0; jj < 4; ++jj) {
      const int t = c * CHUNK_ + crow0 + jj;
      yb[((size_t)(b * T_ + t) * H_ + h) * D_ + d] = rnbf(acc2[et][jj] * inv[jj]);
    }
  }
}

// ---------------------------------------------------------------------------
extern "C" void kernel_launch(void* const* d_in, const int* in_sizes, int n_in,
                              void* d_out, int out_size, void* d_ws, size_t ws_size,
                              hipStream_t stream) {
  const float* x = (const float*)d_in[0];
  const float* w_attn = (const float*)d_in[1];
  const float* w_proj = (const float*)d_in[2];
  float* out = (float*)d_out;

  ushort* xb = (ushort*)d_ws;                        // [8192,1024]
  ushort* wab = xb + (size_t)M_ * E_;                // [3072,1024]
  ushort* wpb = wab + (size_t)3 * E_ * E_;           // [1024,1024]
  ushort* qb = wpb + (size_t)E_ * E_;                // [bh][t][d]
  ushort* kbm = qb + (size_t)M_ * E_;                // [bh][t][d]
  ushort* kT = kbm + (size_t)M_ * E_;                // [bh][d][t]
  ushort* vT = kT + (size_t)M_ * E_;                 // [bh][d][t]
  ushort* yb = vT + (size_t)M_ * E_;                 // [B,T,H,D]
  ushort* STb = yb + (size_t)M_ * E_;                // [bh][c][e][d] bf16
  float* Schunk = (float*)(STb + (size_t)BH_ * NC_ * 4096);  // fp32
  float* zpart = Schunk + (size_t)BH_ * NC_ * 4096;  // [bh][c][2][64]
  float* zout = zpart + (size_t)BH_ * NC_ * 2 * 64;  // [bh][c][64]

  k_cvt<<<8192, 256, 0, stream>>>(x, xb, (M_ * E_) / 4);
  k_cvt<<<3072, 256, 0, stream>>>(w_attn, wab, (3 * E_ * E_) / 4);
  k_cvt<<<1024, 256, 0, stream>>>(w_proj, wpb, (E_ * E_) / 4);

  hipFuncSetAttribute((const void*)k_qkv2,
                      hipFuncAttributeMaxDynamicSharedMemorySize, 73728);
  hipFuncSetAttribute((const void*)k_proj2,
                      hipFuncAttributeMaxDynamicSharedMemorySize, 73728);

  k_qkv2<<<768, 512, 73728, stream>>>(xb, wab, qb, kbm, kT, vT, zpart);
  k_stats<<<1024, 256, 0, stream>>>(kT, vT, Schunk);
  k_prefix<<<64, 256, 0, stream>>>(Schunk, STb, zpart, zout);
  k_out<<<1024, 512, 0, stream>>>(qb, kbm, vT, STb, zout, yb);
  k_proj2<<<256, 512, 73728, stream>>>(yb, wpb, out);
}

// Round 6
// 128.899 us; speedup vs baseline: 7.8603x; 1.1603x over previous
//
#include <hip/hip_runtime.h>
#include <math.h>

#define B_ 4
#define T_ 2048
#define E_ 1024
#define H_ 16
#define D_ 64
#define CHUNK_ 128
#define NC_ 16
#define BH_ (B_ * H_)   // 64
#define M_ (B_ * T_)    // 8192

typedef __attribute__((ext_vector_type(8))) short bf16x8;
typedef __attribute__((ext_vector_type(4))) float f32x4;

__device__ __forceinline__ ushort rnbf(float f) {
  unsigned u = __float_as_uint(f);
  unsigned r = (u + 0x7FFFu + ((u >> 16) & 1u)) >> 16;
  return (ushort)r;
}

__device__ __forceinline__ float bf2f(short s) {
  return __uint_as_float(((unsigned)(ushort)s) << 16);
}

__device__ __forceinline__ void gload_lds16(const void* g, void* l) {
  __builtin_amdgcn_global_load_lds(
      (const __attribute__((address_space(1))) unsigned int*)g,
      (__attribute__((address_space(3))) unsigned int*)l, 16, 0, 0);
}

#define VMW(N) do { asm volatile("s_waitcnt vmcnt(" #N ")" ::: "memory"); \
                    __builtin_amdgcn_sched_barrier(0); } while (0)
#define BARR() do { __builtin_amdgcn_s_barrier(); \
                    __builtin_amdgcn_sched_barrier(0); } while (0)

// ---------------------------------------------------------------------------
// fused fp32 -> bf16 conversion for x, w_attn, w_proj (one launch)
// ---------------------------------------------------------------------------
#define N4X_ (M_ * E_ / 4)           // 2097152
#define N4A_ (3 * E_ * E_ / 4)       // 786432
#define N4P_ (E_ * E_ / 4)           // 262144
__global__ __launch_bounds__(256) void k_cvt3(
    const float* __restrict__ x, const float* __restrict__ wa,
    const float* __restrict__ wp, ushort* __restrict__ xb,
    ushort* __restrict__ wab, ushort* __restrict__ wpb) {
  int i = blockIdx.x * 256 + threadIdx.x;
  const float* src;
  ushort* dst;
  int off;
  if (i < N4X_) { src = x; dst = xb; off = i; }
  else if (i < N4X_ + N4A_) { src = wa; dst = wab; off = i - N4X_; }
  else { src = wp; dst = wpb; off = i - (N4X_ + N4A_); }
  float4 v = ((const float4*)src)[off];
  ushort4 o;
  o.x = rnbf(v.x); o.y = rnbf(v.y); o.z = rnbf(v.z); o.w = rnbf(v.w);
  ((ushort4*)dst)[off] = o;
}

// ---------------------------------------------------------------------------
// Pipelined MFMA GEMM core: C 128x256 tile = A[128xK] x B[256xK]^T, K=1024.
// 8 waves (2M x 4N). BK=32 slabs, 3-deep rotation (72 KB LDS, 2 blocks/CU).
// Per phase: VMW(3), barrier, 8 ds_read_b128 (chunk-XOR swizzled), stage
// slot t+2, 16 MFMA (setprio-wrapped).
// ---------------------------------------------------------------------------
#define STG(sl_, tt_) { \
  gload_lds16(Asrc + (tt_) * 32, &lds[(sl_) * 4096 + tid * 8]); \
  gload_lds16(Bsrc0 + (tt_) * 32, &lds[12288 + (sl_) * 8192 + tid * 8]); \
  gload_lds16(Bsrc1 + (tt_) * 32, &lds[12288 + (sl_) * 8192 + 4096 + tid * 8]); }

#define LDFRAGS(sl_) \
  const ushort* pa = &lds[(sl_) * 4096 + aOff]; \
  a0 = *(const bf16x8*)pa;          a1 = *(const bf16x8*)(pa + 512); \
  a2 = *(const bf16x8*)(pa + 1024); a3 = *(const bf16x8*)(pa + 1536); \
  const ushort* pb = &lds[12288 + (sl_) * 8192 + bOff]; \
  b0 = *(const bf16x8*)pb;          b1 = *(const bf16x8*)(pb + 512); \
  b2 = *(const bf16x8*)(pb + 1024); b3 = *(const bf16x8*)(pb + 1536);

#define MM(i, j, A_, B_) \
  acc[i][j] = __builtin_amdgcn_mfma_f32_16x16x32_bf16(A_, B_, acc[i][j], 0, 0, 0)
#define MFMA16() do { __builtin_amdgcn_s_setprio(1); \
  MM(0,0,a0,b0); MM(0,1,a0,b1); MM(0,2,a0,b2); MM(0,3,a0,b3); \
  MM(1,0,a1,b0); MM(1,1,a1,b1); MM(1,2,a1,b2); MM(1,3,a1,b3); \
  MM(2,0,a2,b0); MM(2,1,a2,b1); MM(2,2,a2,b2); MM(2,3,a2,b3); \
  MM(3,0,a3,b0); MM(3,1,a3,b1); MM(3,2,a3,b2); MM(3,3,a3,b3); \
  __builtin_amdgcn_s_setprio(0); } while (0)

__device__ __forceinline__ void pipe_gemm(const ushort* __restrict__ Ag,
                                          const ushort* __restrict__ Bg,
                                          ushort* lds, f32x4 acc[4][4]) {
  const int tid = threadIdx.x;
  const int l = tid & 63, wv = tid >> 6;
  const int wm = wv >> 2, wn = wv & 3;
  const int c16 = l & 15, g4 = l >> 4;
  const int gch = (tid & 3) ^ ((tid >> 3) & 3);
  const ushort* Asrc = Ag + (size_t)(tid >> 2) * 1024 + gch * 8;
  const ushort* Bsrc0 = Bg + (size_t)(tid >> 2) * 1024 + gch * 8;
  const ushort* Bsrc1 = Bsrc0 + (size_t)128 * 1024;
  const int xq = (c16 >> 1) & 3;
  const int aOff = (wm * 64 + c16) * 32 + ((g4 ^ xq) << 3);
  const int bOff = (wn * 64 + c16) * 32 + ((g4 ^ xq) << 3);

  STG(0, 0);
  STG(1, 1);
  int sl = 0;
#pragma unroll 3
  for (int t = 0; t < 30; ++t) {
    const int slN = sl ? sl - 1 : 2;  // (sl+2)%3
    VMW(3); BARR();
    bf16x8 a0, a1, a2, a3, b0, b1, b2, b3;
    LDFRAGS(sl);
    STG(slN, t + 2);
    MFMA16();
    sl = (sl == 2) ? 0 : sl + 1;
  }
  {  // t=30, slab 0
    VMW(3); BARR();
    bf16x8 a0, a1, a2, a3, b0, b1, b2, b3;
    LDFRAGS(0);
    MFMA16();
  }
  {  // t=31, slab 1
    VMW(0); BARR();
    bf16x8 a0, a1, a2, a3, b0, b1, b2, b3;
    LDFRAGS(1);
    MFMA16();
  }
}

// ---------------------------------------------------------------------------
// Kernel 1: qkv = x @ w_attn^T; phi on q,k; q/k row-major, kT/vT transposed
// (per-wave LDS transpose), z chunk-partials fused.
// XCD-L2 mapping: xcd = b&7 owns bm in [xcd*8, xcd*8+8) x all 12 bn,
// bm-fastest order -> A slice (2 MB) L2-resident, B panel shared by the
// 8 co-running bm-blocks.
// ---------------------------------------------------------------------------
__global__ __launch_bounds__(512, 4) void k_qkv2(
    const ushort* __restrict__ xb, const ushort* __restrict__ wab,
    ushort* __restrict__ qg, ushort* __restrict__ kg,
    ushort* __restrict__ ktg, ushort* __restrict__ vtg,
    float* __restrict__ zp) {
  extern __shared__ ushort lds[];
  const int b = blockIdx.x;
  const int xcd = b & 7, idx = b >> 3;     // idx in [0,96)
  const int bm = xcd * 8 + (idx & 7);      // [0,64)
  const int bn = idx >> 3;                 // [0,12)
  const int tid = threadIdx.x;
  const int wv = tid >> 6, l = tid & 63;
  const int wm = wv >> 2, wn = wv & 3;
  const int c16 = l & 15, g4 = l >> 4;

  f32x4 acc[4][4] = {};
  pipe_gemm(xb + (size_t)bm * 128 * 1024, wab + (size_t)bn * 256 * 1024, lds, acc);

  // ---- epilogue ----
  BARR();  // all LDS reads done; safe to reuse for transpose buffers
  const int colbase = bn * 256 + wn * 64;
  const int which = colbase >> 10;
  const int h = (colbase & 1023) >> 6;
  const int rowbase = bm * 128 + wm * 64;
  const int bidx = rowbase >> 11;
  const int tbase = rowbase & 2047;
  const size_t bh = (size_t)(bidx * 16 + h);
  ushort* wlds = &lds[wv * 4096];  // per-wave 64d x 64t transpose tile
  float zpart[4] = {0.f, 0.f, 0.f, 0.f};
#pragma unroll
  for (int mf = 0; mf < 4; ++mf) {
#pragma unroll
    for (int nf = 0; nf < 4; ++nf) {
      float o[4];
#pragma unroll
      for (int j = 0; j < 4; ++j) {
        float u = acc[mf][nf][j];
        o[j] = (which < 2) ? ((u > 0.f) ? u + 1.f : expf(u)) : u;  // elu+1
      }
      const int d = nf * 16 + c16;
      if (which == 1) zpart[nf] += o[0] + o[1] + o[2] + o[3];
      if (which <= 1) {
        ushort* dst = (which == 0) ? qg : kg;
        const size_t rb = (bh * 2048 + tbase + mf * 16 + g4 * 4) * 64 + d;
#pragma unroll
        for (int j = 0; j < 4; ++j) dst[rb + (size_t)j * 64] = rnbf(o[j]);
      }
      if (which >= 1) {
        const int tb = (mf * 4 + g4) ^ ((d & 3) << 1);
        ushort4 pk;
        pk.x = rnbf(o[0]); pk.y = rnbf(o[1]); pk.z = rnbf(o[2]); pk.w = rnbf(o[3]);
        *(ushort4*)&wlds[d * 64 + tb * 4] = pk;
      }
    }
  }
  if (which == 1) {
    const int cc = tbase >> 7;
#pragma unroll
    for (int nf = 0; nf < 4; ++nf) {
      float zz = zpart[nf];
      zz += __shfl_xor(zz, 16);
      zz += __shfl_xor(zz, 32);
      if (l < 16) zp[((bh * NC_ + cc) * 2 + wm) * 64 + nf * 16 + l] = zz;
    }
  }
  if (which >= 1) {
    asm volatile("s_waitcnt lgkmcnt(0)" ::: "memory");
    __builtin_amdgcn_sched_barrier(0);
    ushort* tg = (which == 1) ? ktg : vtg;
#pragma unroll
    for (int it = 0; it < 8; ++it) {
      const int d = it * 8 + (l >> 3);
      const int t0 = (l & 7) * 8;
      const int blk = ((l & 7) * 2) ^ ((d & 3) << 1);
      bf16x8 vv_ = *(const bf16x8*)&wlds[d * 64 + blk * 4];
      *(bf16x8*)&tg[(bh * 64 + d) * 2048 + tbase + t0] = vv_;
    }
  }
}

// ---------------------------------------------------------------------------
// Kernel 5: out = y @ w_proj^T, same pipelined core, fp32 epilogue.
// XCD-L2 mapping: per-XCD working set = A 2MB + B 2MB (fits 4MB L2).
// ---------------------------------------------------------------------------
__global__ __launch_bounds__(512, 4) void k_proj2(
    const ushort* __restrict__ yb, const ushort* __restrict__ wpb,
    float* __restrict__ out) {
  extern __shared__ ushort lds[];
  const int b = blockIdx.x;
  const int xcd = b & 7, idx = b >> 3;     // idx in [0,32)
  const int bm = xcd * 8 + (idx & 7);      // [0,64)
  const int bn = idx >> 3;                 // [0,4)
  const int tid = threadIdx.x;
  const int wv = tid >> 6, l = tid & 63;
  const int wm = wv >> 2, wn = wv & 3;
  const int c16 = l & 15, g4 = l >> 4;

  f32x4 acc[4][4] = {};
  pipe_gemm(yb + (size_t)bm * 128 * 1024, wpb + (size_t)bn * 256 * 1024, lds, acc);

  const int rowbase = bm * 128 + wm * 64 + g4 * 4;
  const int colbase = bn * 256 + wn * 64 + c16;
#pragma unroll
  for (int mf = 0; mf < 4; ++mf)
#pragma unroll
    for (int nf = 0; nf < 4; ++nf) {
      const size_t base = (size_t)(rowbase + mf * 16) * 1024 + colbase + nf * 16;
#pragma unroll
      for (int j = 0; j < 4; ++j)
        out[base + (size_t)j * 1024] = acc[mf][nf][j];
    }
}

// ---------------------------------------------------------------------------
// Kernel 2 (MFMA): per-chunk  ST[e][d] = sum_t v[t][e] k[t][d]  (fp32 out)
// ---------------------------------------------------------------------------
__global__ __launch_bounds__(256) void k_stats(const ushort* __restrict__ ktg,
                                               const ushort* __restrict__ vtg,
                                               float* __restrict__ Sc) {
  __shared__ __align__(16) ushort kT_s[64 * 128], vT_s[64 * 128];
  const int blk = blockIdx.x;
  const int bh = blk >> 4, c = blk & 15;
  const int tid = threadIdx.x;
  const int w = tid >> 6, l = tid & 63;
  const ushort* ktb = ktg + (size_t)bh * D_ * T_ + c * CHUNK_;
  const ushort* vtb = vtg + (size_t)bh * D_ * T_ + c * CHUNK_;
#pragma unroll
  for (int s2 = 0; s2 < 4; ++s2) {
    const int seg = w * 4 + s2;
    const int row = seg * 4 + (l >> 4);
    const int sb = ((l & 15) ^ (row & 7)) * 8;
    gload_lds16(ktb + (size_t)row * T_ + sb, &kT_s[seg * 512]);
    gload_lds16(vtb + (size_t)row * T_ + sb, &vT_s[seg * 512]);
  }
  __syncthreads();
  const int wr = w >> 1, wc = w & 1;
  f32x4 acc[2][2] = {};
#pragma unroll
  for (int kt = 0; kt < 4; ++kt) {
    const int g = kt * 32 + (l >> 4) * 8;
    bf16x8 av[2], bk[2];
#pragma unroll
    for (int rt = 0; rt < 2; ++rt) {
      const int e = wr * 32 + rt * 16 + (l & 15);
      av[rt] = *(const bf16x8*)&vT_s[e * 128 + (g ^ ((e & 7) << 3))];
    }
#pragma unroll
    for (int ct = 0; ct < 2; ++ct) {
      const int d = wc * 32 + ct * 16 + (l & 15);
      bk[ct] = *(const bf16x8*)&kT_s[d * 128 + (g ^ ((d & 7) << 3))];
    }
#pragma unroll
    for (int rt = 0; rt < 2; ++rt)
#pragma unroll
      for (int ct = 0; ct < 2; ++ct)
        acc[rt][ct] = __builtin_amdgcn_mfma_f32_16x16x32_bf16(av[rt], bk[ct],
                                                              acc[rt][ct], 0, 0, 0);
  }
  float* So = Sc + (size_t)blk * 4096;
#pragma unroll
  for (int rt = 0; rt < 2; ++rt)
#pragma unroll
    for (int ct = 0; ct < 2; ++ct)
#pragma unroll
      for (int jj = 0; jj < 4; ++jj)
        So[(wr * 32 + rt * 16 + (l >> 4) * 4 + jj) * 64 + wc * 32 + ct * 16 + (l & 15)] =
            acc[rt][ct][jj];
}

// ---------------------------------------------------------------------------
// Kernel 3: exclusive prefix over 16 chunks, parallelized.
// blocks 0..255: (bh, quarter) S-scan, all 16 chunk-loads in flight before
// the register-resident scan. blocks 256..319: z-scan per bh.
// ---------------------------------------------------------------------------
__global__ __launch_bounds__(256) void k_prefix2(const float* __restrict__ Sc,
                                                 ushort* __restrict__ STb,
                                                 const float* __restrict__ zp,
                                                 float* __restrict__ zout) {
  const int b = blockIdx.x;
  const int tid = threadIdx.x;
  if (b < 256) {
    const int bh = b >> 2, qt = b & 3;
    const float4* Sb = (const float4*)(Sc + (size_t)bh * NC_ * 4096) + qt * 256 + tid;
    ushort4* Ob = (ushort4*)(STb + (size_t)bh * NC_ * 4096) + qt * 256 + tid;
    float4 v[16];
#pragma unroll
    for (int c = 0; c < NC_; ++c) v[c] = Sb[c * 1024];
    float4 acc = make_float4(0.f, 0.f, 0.f, 0.f);
#pragma unroll
    for (int c = 0; c < NC_; ++c) {
      ushort4 o;
      o.x = rnbf(acc.x); o.y = rnbf(acc.y); o.z = rnbf(acc.z); o.w = rnbf(acc.w);
      Ob[c * 1024] = o;
      acc.x += v[c].x; acc.y += v[c].y; acc.z += v[c].z; acc.w += v[c].w;
    }
  } else {
    const int bh = b - 256;
    if (tid < 16) {
      const float4* zpb = (const float4*)(zp + (size_t)bh * NC_ * 128);
      float4* zob = (float4*)(zout + (size_t)bh * NC_ * 64);
      float4 t0[16], t1[16];
#pragma unroll
      for (int c = 0; c < NC_; ++c) {
        t0[c] = zpb[c * 32 + tid];
        t1[c] = zpb[c * 32 + 16 + tid];
      }
      float4 za = make_float4(0.f, 0.f, 0.f, 0.f);
#pragma unroll
      for (int c = 0; c < NC_; ++c) {
        zob[c * 16 + tid] = za;
        za.x += t0[c].x + t1[c].x; za.y += t0[c].y + t1[c].y;
        za.z += t0[c].z + t1[c].z; za.w += t0[c].w + t1[c].w;
      }
    }
  }
}

// ---------------------------------------------------------------------------
// Kernel 4 (MFMA): per-chunk output -> y bf16 [B,T,H,D]
// ---------------------------------------------------------------------------
__global__ __launch_bounds__(512, 4) void k_out(
    const ushort* __restrict__ qg, const ushort* __restrict__ kg,
    const ushort* __restrict__ vtg, const ushort* __restrict__ STb,
    const float* __restrict__ zg, ushort* __restrict__ yb) {
  __shared__ __align__(16) ushort k_s[128 * 64];
  __shared__ __align__(16) ushort vT_s[64 * 128];
  __shared__ __align__(16) ushort ST_s[64 * 64];
  __shared__ __align__(16) ushort P_s[128 * 128];
  __shared__ float z_s[64];
  __shared__ float dinter_s[128];
  const int blk = blockIdx.x;
  const int bh = blk >> 4, c = blk & 15;
  const int tid = threadIdx.x;
  const int w = tid >> 6, l = tid & 63;

  const ushort* kbase = kg + ((size_t)bh * T_ + c * CHUNK_) * D_;
  const ushort* vbase = vtg + (size_t)bh * D_ * T_ + c * CHUNK_;
  const ushort* sbase = STb + ((size_t)bh * NC_ + c) * 4096;
  {
    int seg = w, row = seg * 8 + (l >> 3);
    gload_lds16(kbase + (size_t)row * 64 + ((l & 7) ^ (row & 7)) * 8, &k_s[seg * 512]);
    seg = w + 8; row = seg * 8 + (l >> 3);
    gload_lds16(kbase + (size_t)row * 64 + ((l & 7) ^ (row & 7)) * 8, &k_s[seg * 512]);
  }
  {
    int seg = w, row = seg * 4 + (l >> 4);
    gload_lds16(vbase + (size_t)row * T_ + ((l & 15) ^ (row & 7)) * 8, &vT_s[seg * 512]);
    seg = w + 8; row = seg * 4 + (l >> 4);
    gload_lds16(vbase + (size_t)row * T_ + ((l & 15) ^ (row & 7)) * 8, &vT_s[seg * 512]);
  }
  {
    const int seg = w, row = seg * 8 + (l >> 3);
    gload_lds16(sbase + (size_t)row * 64 + ((l & 7) ^ (row & 7)) * 8, &ST_s[seg * 512]);
  }
  if (tid < 64) z_s[tid] = zg[((size_t)bh * NC_ + c) * 64 + tid];
  const int arow = w * 16 + (l & 15);
  const ushort* qrow = qg + ((size_t)bh * T_ + c * CHUNK_ + arow) * D_ + (l >> 4) * 8;
  bf16x8 qf0 = *(const bf16x8*)(qrow);
  bf16x8 qf1 = *(const bf16x8*)(qrow + 32);
  __syncthreads();

  f32x4 sc[8] = {};
#pragma unroll
  for (int jt = 0; jt < 8; ++jt) {
    const int j = jt * 16 + (l & 15);
    const int sw = (j & 7) << 3, g = (l >> 4) * 8;
    bf16x8 b0 = *(const bf16x8*)&k_s[j * 64 + (g ^ sw)];
    bf16x8 b1 = *(const bf16x8*)&k_s[j * 64 + ((g + 32) ^ sw)];
    sc[jt] = __builtin_amdgcn_mfma_f32_16x16x32_bf16(qf0, b0, sc[jt], 0, 0, 0);
    sc[jt] = __builtin_amdgcn_mfma_f32_16x16x32_bf16(qf1, b1, sc[jt], 0, 0, 0);
  }
  const int crow0 = w * 16 + (l >> 4) * 4;
  float rsum[4] = {0.f, 0.f, 0.f, 0.f};
#pragma unroll
  for (int jt = 0; jt < 8; ++jt) {
    const int j = jt * 16 + (l & 15);
#pragma unroll
    for (int jj = 0; jj < 4; ++jj) {
      const int i = crow0 + jj;
      float s = (j <= i) ? sc[jt][jj] : 0.f;
      rsum[jj] += s;
      P_s[i * 128 + (j ^ ((i & 7) << 3))] = rnbf(s);
    }
  }
  float di = 0.f;
#pragma unroll
  for (int jj = 0; jj < 8; ++jj) {
    di = fmaf(bf2f(qf0[jj]), z_s[(l >> 4) * 8 + jj], di);
    di = fmaf(bf2f(qf1[jj]), z_s[32 + (l >> 4) * 8 + jj], di);
  }
  di += __shfl_xor(di, 16);
  di += __shfl_xor(di, 32);
  if (l < 16) dinter_s[w * 16 + l] = di;
#pragma unroll
  for (int jj = 0; jj < 4; ++jj) {
    float r = rsum[jj];
    r += __shfl_xor(r, 1); r += __shfl_xor(r, 2);
    r += __shfl_xor(r, 4); r += __shfl_xor(r, 8);
    rsum[jj] = r;
  }
  __syncthreads();

  f32x4 acc2[4] = {};
#pragma unroll
  for (int et = 0; et < 4; ++et) {
    const int e = et * 16 + (l & 15);
    const int sw = (e & 7) << 3, g = (l >> 4) * 8;
    bf16x8 s0 = *(const bf16x8*)&ST_s[e * 64 + (g ^ sw)];
    bf16x8 s1 = *(const bf16x8*)&ST_s[e * 64 + ((g + 32) ^ sw)];
    acc2[et] = __builtin_amdgcn_mfma_f32_16x16x32_bf16(qf0, s0, acc2[et], 0, 0, 0);
    acc2[et] = __builtin_amdgcn_mfma_f32_16x16x32_bf16(qf1, s1, acc2[et], 0, 0, 0);
  }
  const int prow = w * 16 + (l & 15);
  const int psw = (prow & 7) << 3;
#pragma unroll
  for (int jkt = 0; jkt < 4; ++jkt) {
    bf16x8 pa = *(const bf16x8*)&P_s[prow * 128 + ((jkt * 32 + (l >> 4) * 8) ^ psw)];
#pragma unroll
    for (int et = 0; et < 4; ++et) {
      const int e = et * 16 + (l & 15);
      bf16x8 bv = *(const bf16x8*)&vT_s[e * 128 +
                                        ((jkt * 32 + (l >> 4) * 8) ^ ((e & 7) << 3))];
      acc2[et] = __builtin_amdgcn_mfma_f32_16x16x32_bf16(pa, bv, acc2[et], 0, 0, 0);
    }
  }
  float inv[4];
#pragma unroll
  for (int jj = 0; jj < 4; ++jj)
    inv[jj] = 1.0f / (rsum[jj] + dinter_s[crow0 + jj] + 1e-6f);
  const int b = bh >> 4, h = bh & 15;
#pragma unroll
  for (int et = 0; et < 4; ++et) {
    const int d = et * 16 + (l & 15);
#pragma unroll
    for (int jj = 0; jj < 4; ++jj) {
      const int t = c * CHUNK_ + crow0 + jj;
      yb[((size_t)(b * T_ + t) * H_ + h) * D_ + d] = rnbf(acc2[et][jj] * inv[jj]);
    }
  }
}

// ---------------------------------------------------------------------------
extern "C" void kernel_launch(void* const* d_in, const int* in_sizes, int n_in,
                              void* d_out, int out_size, void* d_ws, size_t ws_size,
                              hipStream_t stream) {
  const float* x = (const float*)d_in[0];
  const float* w_attn = (const float*)d_in[1];
  const float* w_proj = (const float*)d_in[2];
  float* out = (float*)d_out;

  ushort* xb = (ushort*)d_ws;                        // [8192,1024]
  ushort* wab = xb + (size_t)M_ * E_;                // [3072,1024]
  ushort* wpb = wab + (size_t)3 * E_ * E_;           // [1024,1024]
  ushort* qb = wpb + (size_t)E_ * E_;                // [bh][t][d]
  ushort* kbm = qb + (size_t)M_ * E_;                // [bh][t][d]
  ushort* kT = kbm + (size_t)M_ * E_;                // [bh][d][t]
  ushort* vT = kT + (size_t)M_ * E_;                 // [bh][d][t]
  ushort* yb = vT + (size_t)M_ * E_;                 // [B,T,H,D]
  ushort* STb = yb + (size_t)M_ * E_;                // [bh][c][e][d] bf16
  float* Schunk = (float*)(STb + (size_t)BH_ * NC_ * 4096);  // fp32
  float* zpart = Schunk + (size_t)BH_ * NC_ * 4096;  // [bh][c][2][64]
  float* zout = zpart + (size_t)BH_ * NC_ * 2 * 64;  // [bh][c][64]

  k_cvt3<<<12288, 256, 0, stream>>>(x, w_attn, w_proj, xb, wab, wpb);

  hipFuncSetAttribute((const void*)k_qkv2,
                      hipFuncAttributeMaxDynamicSharedMemorySize, 73728);
  hipFuncSetAttribute((const void*)k_proj2,
                      hipFuncAttributeMaxDynamicSharedMemorySize, 73728);

  k_qkv2<<<768, 512, 73728, stream>>>(xb, wab, qb, kbm, kT, vT, zpart);
  k_stats<<<1024, 256, 0, stream>>>(kT, vT, Schunk);
  k_prefix2<<<320, 256, 0, stream>>>(Schunk, STb, zpart, zout);
  k_out<<<1024, 512, 0, stream>>>(qb, kbm, vT, STb, zout, yb);
  k_proj2<<<256, 512, 73728, stream>>>(yb, wpb, out);
}